// Round 7
// baseline (2038.350 us; speedup 1.0000x reference)
//
#include <hip/hip_runtime.h>
#include <hip/hip_bf16.h>
#include <math.h>

// Problem constants
#define BB 4
#define SEQL 12
#define NN 1024
#define SEGL 3
#define SEGN 4
#define HID 64
#define FFD 2048
#define DKK 32
#define NHH 8
#define HDD 8

using bf16 = __hip_bfloat16;
__device__ __forceinline__ float b2f(bf16 v) { return __bfloat162float(v); }

typedef __attribute__((ext_vector_type(8))) short s8v;   // 8 bf16 (4 VGPRs)
typedef __attribute__((ext_vector_type(4))) float f4v;   // MFMA C/D
typedef __attribute__((ext_vector_type(4))) unsigned short u4v;

__device__ __forceinline__ unsigned short f2b(float f) {
  bf16 h = __float2bfloat16(f);
  unsigned short u; __builtin_memcpy(&u, &h, 2); return u;
}
__device__ __forceinline__ float us2f(unsigned short u) {
  unsigned int e = ((unsigned int)u) << 16;
  float f; __builtin_memcpy(&f, &e, 4); return f;
}

// dtype-templated loads: F=1 fp32 storage, F=0 bf16 storage
template <int F>
__device__ __forceinline__ float ldw(const void* p, long i) {
  if (F) return ((const float*)p)[i];
  return b2f(((const bf16*)p)[i]);
}
template <int F>
__device__ __forceinline__ s8v ldfrag(const void* p, long elemOff) {
  if (F) {
    const float* fp = (const float*)p + elemOff;
    f4v u = *(const f4v*)fp, v = *(const f4v*)(fp + 4);
    s8v t;
    t[0]=f2b(u[0]); t[1]=f2b(u[1]); t[2]=f2b(u[2]); t[3]=f2b(u[3]);
    t[4]=f2b(v[0]); t[5]=f2b(v[1]); t[6]=f2b(v[2]); t[7]=f2b(v[3]);
    return t;
  }
  return *(const s8v*)((const unsigned short*)p + elemOff);
}
template <int F>
__device__ __forceinline__ f4v ldb4(const void* p, long i) {  // 4 consecutive vals
  if (F) return *(const f4v*)((const float*)p + i);
  u4v u = *(const u4v*)((const unsigned short*)p + i);
  f4v r; r[0]=us2f(u[0]); r[1]=us2f(u[1]); r[2]=us2f(u[2]); r[3]=us2f(u[3]);
  return r;
}

// ---------------------------------------------------------------- zero-fill d_out (guard path)
__global__ void k_zero(unsigned short* __restrict__ o, int n) {
  int i = blockIdx.x * 256 + threadIdx.x;
  if (i < n) o[i] = 0;
}

// ---------------------------------------------------------------- detect dtype
__global__ void k_detect(const void* __restrict__ x0, int* __restrict__ flag) {
  int t = threadIdx.x;
  int bad = 0;
  const bf16* p = (const bf16*)x0;
  for (int i = t; i < 512; i += 256) {
    float a = fabsf(b2f(p[i]));
    if (!(a < 1e4f) || (a != 0.f && a < 1e-4f)) bad = 1;
  }
  __shared__ int tot;
  if (t == 0) tot = 0;
  __syncthreads();
  unsigned long long m = __ballot(bad);
  if ((t & 63) == 0) atomicAdd(&tot, __popcll(m));
  __syncthreads();
  if (t == 0) *flag = (tot > 64) ? 1 : 0;   // 1 = fp32 storage, 0 = bf16
}

// ---------------------------------------------------------------- patch embed
template <int F>
__device__ __forceinline__ void patch_body(const void* __restrict__ x,
    const void* __restrict__ pw, long opw, const void* __restrict__ pb, long opb,
    float* __restrict__ z) {
  int b = blockIdx.x >> 10, n = blockIdx.x & 1023;
  int g = threadIdx.x >> 6, h = threadIdx.x & 63;
  float acc = ldw<F>(pb, opb + h);
#pragma unroll
  for (int l = 0; l < SEGL; ++l)
    acc += ldw<F>(x, (long)(b*SEQL + g*SEGL + l)*NN + n) * ldw<F>(pw, opw + h*SEGL + l);
  int i2 = h >> 1;
  float dv = expf((float)(2*i2) * (-logf(10000.f) / (float)HID));
  float ang = (float)g * dv;
  acc += (h & 1) ? cosf(ang) : sinf(ang);
  z[((long)(b*NN + n)*SEGN + g)*HID + h] = acc;
}
__global__ __launch_bounds__(256) void k_patch(const void* __restrict__ x,
    const void* __restrict__ pw, long opw, const void* __restrict__ pb, long opb,
    float* __restrict__ z, const int* __restrict__ flag) {
  if (*flag) patch_body<1>(x, pw, opw, pb, opb, z);
  else       patch_body<0>(x, pw, opw, pb, opb, z);
}

// ---------------------------------------------------------------- temporal MHA + LN1
struct TattnS {
  float xr[SEGN][HID];
  float qkv[SEGN][3*HID];
  float ao[SEGN][HID];
  float mst[SEGN][2];
};
template <int F>
__device__ __forceinline__ void tattn_body(float* __restrict__ z,
    const void* __restrict__ W, long oW, const void* __restrict__ bqkv, long obq,
    const void* __restrict__ WO, long oWO, const void* __restrict__ bo, long obo,
    const void* __restrict__ g1, long og1, const void* __restrict__ b1, long ob1,
    TattnS& sm) {
  int h = threadIdx.x;
  float* zp = z + (long)blockIdx.x * SEGN * HID;
#pragma unroll
  for (int g = 0; g < SEGN; ++g) sm.xr[g][h] = zp[g*HID + h];
  __syncthreads();
#pragma unroll
  for (int j = 0; j < 3; ++j) {
    int c = j*HID + h;
    long wr = oW + (long)c*HID;
    float a0=0,a1=0,a2=0,a3=0;
    for (int k = 0; k < HID; ++k) {
      float w = ldw<F>(W, wr + k);
      a0 += sm.xr[0][k]*w; a1 += sm.xr[1][k]*w; a2 += sm.xr[2][k]*w; a3 += sm.xr[3][k]*w;
    }
    float bb = ldw<F>(bqkv, obq + c);
    sm.qkv[0][c]=a0+bb; sm.qkv[1][c]=a1+bb; sm.qkv[2][c]=a2+bb; sm.qkv[3][c]=a3+bb;
  }
  __syncthreads();
  if (h < NHH*SEGN) {
    int head = h >> 2, qt = h & 3;
    const float scale = 0.3535533905932738f;   // 1/sqrt(8)
    float s[SEGN]; float mx = -1e30f;
#pragma unroll
    for (int kt = 0; kt < SEGN; ++kt) {
      float d = 0;
#pragma unroll
      for (int e = 0; e < HDD; ++e) d += sm.qkv[qt][head*HDD+e]*sm.qkv[kt][HID+head*HDD+e];
      s[kt] = d*scale; mx = fmaxf(mx, s[kt]);
    }
    float se = 0;
#pragma unroll
    for (int kt = 0; kt < SEGN; ++kt) { s[kt] = expf(s[kt]-mx); se += s[kt]; }
    float inv = 1.f/se;
#pragma unroll
    for (int e = 0; e < HDD; ++e) {
      float o = 0;
#pragma unroll
      for (int kt = 0; kt < SEGN; ++kt) o += s[kt]*sm.qkv[kt][2*HID+head*HDD+e];
      sm.ao[qt][head*HDD+e] = o*inv;
    }
  }
  __syncthreads();
  float y[SEGN];
  {
    long wr = oWO + (long)h*HID;
    float bb = ldw<F>(bo, obo + h);
#pragma unroll
    for (int g = 0; g < SEGN; ++g) {
      float a = bb;
      for (int k = 0; k < HID; ++k) a += sm.ao[g][k]*ldw<F>(WO, wr + k);
      y[g] = sm.xr[g][h] + a;    // residual
    }
  }
  __syncthreads();
#pragma unroll
  for (int g = 0; g < SEGN; ++g) sm.xr[g][h] = y[g];
  __syncthreads();
  if (h < SEGN) {
    float m = 0;
    for (int k = 0; k < HID; ++k) m += sm.xr[h][k];
    m *= (1.f/HID);
    float v = 0;
    for (int k = 0; k < HID; ++k) { float d = sm.xr[h][k]-m; v += d*d; }
    sm.mst[h][0] = m; sm.mst[h][1] = rsqrtf(v*(1.f/HID) + 1e-5f);
  }
  __syncthreads();
  float gg = ldw<F>(g1, og1 + h), bb2 = ldw<F>(b1, ob1 + h);
#pragma unroll
  for (int g = 0; g < SEGN; ++g)
    zp[g*HID + h] = (y[g]-sm.mst[g][0])*sm.mst[g][1]*gg + bb2;
}
__global__ __launch_bounds__(64) void k_tattn(float* __restrict__ z,
    const void* W, long oW, const void* bqkv, long obq,
    const void* WO, long oWO, const void* bo, long obo,
    const void* g1, long og1, const void* b1, long ob1,
    const int* __restrict__ flag) {
  __shared__ TattnS sm;
  if (*flag) tattn_body<1>(z, W, oW, bqkv, obq, WO, oWO, bo, obo, g1, og1, b1, ob1, sm);
  else       tattn_body<0>(z, W, oW, bqkv, obq, WO, oWO, bo, obo, g1, og1, b1, ob1, sm);
}

// ---------------------------------------------------------------- FF via MFMA bf16 (v3)
// 16 rows/block, 1024 blocks (4/CU). Wave w owns hidden slice [w*512,(w+1)*512):
// GEMM1 -> relu -> PRIVATE per-wave LDS -> GEMM2 partial, zero barriers in the
// K-loop. One barrier at the end for the cross-wave Y^T reduction.
#define FRW 16
template <int F>
__device__ __forceinline__ void ffmfma_body(float* __restrict__ x,
    const void* __restrict__ W1, long o1, const void* __restrict__ B1, long ob1,
    const void* __restrict__ W2, long o2, const void* __restrict__ B2, long ob2,
    const void* __restrict__ G, long og, const void* __restrict__ Bt, long obt,
    char* ldsbuf) {
  int tid = threadIdx.x;
  int w = tid >> 6, lane = tid & 63;
  int col = lane & 15, quad = lane >> 4;
  long r0 = (long)blockIdx.x * FRW;
  unsigned short* hcw = (unsigned short*)(ldsbuf + w*8448);   // [16 xrow][264] shorts

  // X B-fragments (n=xrow=col, k=ks*32+quad*8), constant across the K-loop
  s8v bx[2];
  {
    const float* xr = x + (r0 + col) * HID;
#pragma unroll
    for (int ks = 0; ks < 2; ++ks) {
      const float* p = xr + ks*32 + quad*8;
      f4v u = *(const f4v*)p, v = *(const f4v*)(p + 4);
      s8v t;
      t[0]=f2b(u[0]); t[1]=f2b(u[1]); t[2]=f2b(u[2]); t[3]=f2b(u[3]);
      t[4]=f2b(v[0]); t[5]=f2b(v[1]); t[6]=f2b(v[2]); t[7]=f2b(v[3]);
      bx[ks] = t;
    }
  }

  f4v acc[4];
#pragma unroll
  for (int m = 0; m < 4; ++m) acc[m] = (f4v){0.f,0.f,0.f,0.f};

  const int hb0 = w * 512;
  for (int c = 0; c < 2; ++c) {
    const int hbase = hb0 + c*256;
    // ---- GEMM1 (S^T = W1 @ X^T) over this wave's 256-hidden chunk
#pragma unroll 4
    for (int t = 0; t < 16; ++t) {
      int h0 = hbase + t*16;
      f4v sv = (f4v){0.f,0.f,0.f,0.f};
#pragma unroll
      for (int ks = 0; ks < 2; ++ks) {
        s8v aw = ldfrag<F>(W1, o1 + (long)(h0 + col)*HID + ks*32 + quad*8);
        sv = __builtin_amdgcn_mfma_f32_16x16x32_bf16(aw, bx[ks], sv, 0, 0, 0);
      }
      f4v bv = ldb4<F>(B1, ob1 + h0 + quad*4);
      unsigned short pk[4];
#pragma unroll
      for (int r = 0; r < 4; ++r) pk[r] = f2b(fmaxf(sv[r] + bv[r], 0.f));
      *(unsigned long long*)&hcw[col*264 + t*16 + quad*4] =
        (unsigned long long)pk[0] | ((unsigned long long)pk[1] << 16) |
        ((unsigned long long)pk[2] << 32) | ((unsigned long long)pk[3] << 48);
    }
    // ---- GEMM2 partial (Y^T += W2 @ Hc^T), K = this chunk
#pragma unroll 2
    for (int ks2 = 0; ks2 < 8; ++ks2) {
      s8v bh = *(const s8v*)&hcw[col*264 + ks2*32 + quad*8];
#pragma unroll
      for (int m = 0; m < 4; ++m) {
        s8v aw = ldfrag<F>(W2, o2 + (long)(m*16 + col)*FFD + hbase + ks2*32 + quad*8);
        acc[m] = __builtin_amdgcn_mfma_f32_16x16x32_bf16(aw, bh, acc[m], 0, 0, 0);
      }
    }
  }

  // ---- stage partial Y^T into own region (wave-local reuse of hcw space)
  float* yrw = (float*)(ldsbuf + w*8448);                     // [16 xrow][68] floats
#pragma unroll
  for (int m = 0; m < 4; ++m)
    *(f4v*)&yrw[col*68 + m*16 + quad*4] = acc[m];
  __syncthreads();
  // ---- reduce across waves + bias + residual + LN; wave w owns rows w*4..w*4+3
  float gg = ldw<F>(G, og + lane), bbt = ldw<F>(Bt, obt + lane);
  float b2v = ldw<F>(B2, ob2 + lane);
#pragma unroll
  for (int rr = 0; rr < 4; ++rr) {
    int rl = w*4 + rr;
    long grow = r0 + rl;
    float val = b2v + x[grow*HID + lane];
#pragma unroll
    for (int w2 = 0; w2 < 4; ++w2)
      val += ((const float*)(ldsbuf + w2*8448))[rl*68 + lane];
    float s = val;
#pragma unroll
    for (int off = 32; off; off >>= 1) s += __shfl_xor(s, off);
    float m = s * (1.f/HID);
    float d = val - m;
    float sq = d*d;
#pragma unroll
    for (int off = 32; off; off >>= 1) sq += __shfl_xor(sq, off);
    float rv = rsqrtf(sq*(1.f/HID) + 1e-5f);
    x[grow*HID + lane] = d*rv*gg + bbt;
  }
}
__global__ __launch_bounds__(256) void k_ffmfma(float* __restrict__ x,
    const void* W1, long o1, const void* B1, long ob1,
    const void* W2, long o2, const void* B2, long ob2,
    const void* G, long og, const void* Bt, long obt,
    const int* __restrict__ flag) {
  __shared__ __attribute__((aligned(16))) char ldsbuf[4*8448];
  if (*flag) ffmfma_body<1>(x, W1, o1, B1, ob1, W2, o2, B2, ob2, G, og, Bt, obt, ldsbuf);
  else       ffmfma_body<0>(x, W1, o1, B1, ob1, W2, o2, B2, ob2, G, og, Bt, obt, ldsbuf);
}

// ---------------------------------------------------------------- graph qkv proj
template <int F>
__device__ __forceinline__ void gqkv_body(const float* __restrict__ z,
    const void* __restrict__ wq, long oq, const void* __restrict__ wk, long ok,
    const void* __restrict__ wv, long ov,
    unsigned short* __restrict__ q, unsigned short* __restrict__ k,
    float* __restrict__ v, float* xs) {
  int bg = blockIdx.x >> 10, n = blockIdx.x & 1023;
  int b = bg >> 2, g = bg & 3;
  const float* zp = z + ((long)(b*NN + n)*SEGN + g)*HID;
  int t = threadIdx.x;
  if (t < HID) xs[t] = zp[t];
  __syncthreads();
  long r = (long)bg*NN + n;
  if (t < 32) {
    long wr = oq + (long)t*HID; float a = 0;
    for (int e = 0; e < HID; ++e) a += xs[e]*ldw<F>(wq, wr + e);
    q[r*DKK + t] = f2b(a);
  } else if (t < 64) {
    long wr = ok + (long)(t-32)*HID; float a = 0;
    for (int e = 0; e < HID; ++e) a += xs[e]*ldw<F>(wk, wr + e);
    k[r*DKK + (t-32)] = f2b(a);
  } else {
    long wr = ov + (long)(t-64)*HID; float a = 0;
    for (int e = 0; e < HID; ++e) a += xs[e]*ldw<F>(wv, wr + e);
    v[r*HID + (t-64)] = a;
  }
}
__global__ __launch_bounds__(128) void k_gqkv(const float* __restrict__ z,
    const void* wq, long oq, const void* wk, long ok, const void* wv, long ov,
    unsigned short* q, unsigned short* k, float* v, const int* __restrict__ flag) {
  __shared__ float xs[HID];
  if (*flag) gqkv_body<1>(z, wq, oq, wk, ok, wv, ov, q, k, v, xs);
  else       gqkv_body<0>(z, wq, oq, wk, ok, wv, ov, q, k, v, xs);
}

// ---------------------------------------------------------------- graph attention (flash-MFMA)
__global__ __launch_bounds__(256) void k_gattn(float* __restrict__ z,
    const unsigned short* __restrict__ qb, const unsigned short* __restrict__ kb,
    const float* __restrict__ vb,
    const void* __restrict__ g1, long og1, const void* __restrict__ b1, long ob1,
    const int* __restrict__ flag) {
  int f = *flag;
  __shared__ unsigned short vt[64][72];   // [vdim][key]
  __shared__ unsigned short pl[64][72];   // [q_local][key]
  __shared__ float ob[64][66];
  int tid = threadIdx.x;
  int wv = tid >> 6, lane = tid & 63;
  int col = lane & 15, quad = lane >> 4;
  int bg = blockIdx.x >> 4;
  int n0 = (blockIdx.x & 15) * 64;
  long gbase = (long)bg * NN;

  s8v aq = *(const s8v*)(qb + (gbase + n0 + wv*16 + col)*DKK + quad*8);

  f4v acc[4];
#pragma unroll
  for (int t = 0; t < 4; ++t) acc[t] = (f4v){0.f,0.f,0.f,0.f};
  float mrow[4] = {-1e30f,-1e30f,-1e30f,-1e30f};
  float lrow[4] = {0.f,0.f,0.f,0.f};
  const float rs = 0.17677669529663687f;   // 1/sqrt(32)

  int kp = (tid & 31) * 2, dg = tid >> 5;

  for (int c0 = 0; c0 < NN; c0 += 64) {
    __syncthreads();
    {
      const float* vr0 = vb + (gbase + c0 + kp)*HID + dg*8;
      const float* vr1 = vr0 + HID;
      f4v u0 = *(const f4v*)vr0, u1 = *(const f4v*)(vr0 + 4);
      f4v w0 = *(const f4v*)vr1, w1 = *(const f4v*)(vr1 + 4);
#pragma unroll
      for (int i = 0; i < 4; ++i) {
        unsigned int p0 = (unsigned int)f2b(u0[i]) | ((unsigned int)f2b(w0[i]) << 16);
        unsigned int p1 = (unsigned int)f2b(u1[i]) | ((unsigned int)f2b(w1[i]) << 16);
        *(unsigned int*)&vt[dg*8 + i][kp] = p0;
        *(unsigned int*)&vt[dg*8 + 4 + i][kp] = p1;
      }
    }
    f4v s[4];
#pragma unroll
    for (int nt = 0; nt < 4; ++nt) {
      s8v bk = *(const s8v*)(kb + (gbase + c0 + nt*16 + col)*DKK + quad*8);
      s[nt] = __builtin_amdgcn_mfma_f32_16x16x32_bf16(aq, bk,
                (f4v){0.f,0.f,0.f,0.f}, 0, 0, 0);
    }
#pragma unroll
    for (int r = 0; r < 4; ++r) {
      float s0 = s[0][r]*rs, s1 = s[1][r]*rs, s2 = s[2][r]*rs, s3 = s[3][r]*rs;
      float mc = fmaxf(fmaxf(s0, s1), fmaxf(s2, s3));
#pragma unroll
      for (int off = 1; off < 16; off <<= 1) mc = fmaxf(mc, __shfl_xor(mc, off));
      float mn = fmaxf(mrow[r], mc);
      float al = expf(mrow[r] - mn);
      mrow[r] = mn;
      float p0 = expf(s0 - mn), p1 = expf(s1 - mn), p2 = expf(s2 - mn), p3 = expf(s3 - mn);
      float su = p0 + p1 + p2 + p3;
#pragma unroll
      for (int off = 1; off < 16; off <<= 1) su += __shfl_xor(su, off);
      lrow[r] = lrow[r]*al + su;
#pragma unroll
      for (int t = 0; t < 4; ++t) acc[t][r] *= al;
      int row = wv*16 + quad*4 + r;
      pl[row][col]      = f2b(p0);
      pl[row][16 + col] = f2b(p1);
      pl[row][32 + col] = f2b(p2);
      pl[row][48 + col] = f2b(p3);
    }
    __syncthreads();
#pragma unroll
    for (int ks = 0; ks < 2; ++ks) {
      s8v ap = *(const s8v*)&pl[wv*16 + col][ks*32 + quad*8];
#pragma unroll
      for (int nt = 0; nt < 4; ++nt) {
        s8v bv = *(const s8v*)&vt[nt*16 + col][ks*32 + quad*8];
        acc[nt] = __builtin_amdgcn_mfma_f32_16x16x32_bf16(ap, bv, acc[nt], 0, 0, 0);
      }
    }
  }

  float il[4];
#pragma unroll
  for (int r = 0; r < 4; ++r) il[r] = 1.f / lrow[r];
#pragma unroll
  for (int t = 0; t < 4; ++t) {
    int row = wv*16 + quad*4;
#pragma unroll
    for (int r = 0; r < 4; ++r)
      ob[row + r][t*16 + col] = acc[t][r] * il[r];
  }
  __syncthreads();
  int b = bg >> 2, g = bg & 3;
  float gg = f ? ((const float*)g1)[og1 + lane] : b2f(((const bf16*)g1)[og1 + lane]);
  float bb = f ? ((const float*)b1)[ob1 + lane] : b2f(((const bf16*)b1)[ob1 + lane]);
#pragma unroll
  for (int rr = 0; rr < 16; ++rr) {
    int rl = wv*16 + rr;
    int n = n0 + rl;
    float val = ob[rl][lane];
    float s = val;
#pragma unroll
    for (int off = 32; off; off >>= 1) s += __shfl_xor(s, off);
    float m = s*(1.f/HID);
    float d = val - m, sq = d*d;
#pragma unroll
    for (int off = 32; off; off >>= 1) sq += __shfl_xor(sq, off);
    float r = rsqrtf(sq*(1.f/HID) + 1e-5f);
    float* zp = z + ((long)(b*NN + n)*SEGN + g)*HID;
    zp[lane] = d*r*gg + bb + zp[lane];   // LN(att) + x
  }
}

// ---------------------------------------------------------------- pool over segments
__global__ __launch_bounds__(64) void k_pool(const float* __restrict__ z,
    float* __restrict__ enc, int s) {
  int b = blockIdx.x >> 10, n = blockIdx.x & 1023, h = threadIdx.x;
  const float* zp = z + (long)(b*NN + n)*SEGN*HID;
  float a = 0;
#pragma unroll
  for (int g = 0; g < SEGN; ++g) a += zp[g*HID + h];
  enc[(long)(b*NN + n)*(2*HID) + s*HID + h] = a*0.25f;
}

// ---------------------------------------------------------------- final qkv proj (in_dim=128)
template <int F>
__device__ __forceinline__ void fqkv_body(const float* __restrict__ enc,
    const void* __restrict__ wq, const void* __restrict__ wk,
    const void* __restrict__ wv,
    float* __restrict__ q, float* __restrict__ k, float* __restrict__ v,
    float* xs) {
  long r = blockIdx.x;
  int t = threadIdx.x;
  xs[t] = enc[r*128 + t];
  __syncthreads();
  if (t < 32) {
    long wr = (long)t*128; float a = 0;
    for (int e = 0; e < 128; ++e) a += xs[e]*ldw<F>(wq, wr + e);
    q[r*DKK + t] = a;
  } else if (t < 64) {
    long wr = (long)(t-32)*128; float a = 0;
    for (int e = 0; e < 128; ++e) a += xs[e]*ldw<F>(wk, wr + e);
    k[r*DKK + (t-32)] = a;
  } else {
    long wr = (long)(t-64)*128; float a = 0;
    for (int e = 0; e < 128; ++e) a += xs[e]*ldw<F>(wv, wr + e);
    v[r*HID + (t-64)] = a;
  }
}
__global__ __launch_bounds__(128) void k_fqkv(const float* __restrict__ enc,
    const void* wq, const void* wk, const void* wv,
    float* q, float* k, float* v, const int* __restrict__ flag) {
  __shared__ float xs[2*HID];
  if (*flag) fqkv_body<1>(enc, wq, wk, wv, q, k, v, xs);
  else       fqkv_body<0>(enc, wq, wk, wv, q, k, v, xs);
}

// ---------------------------------------------------------------- final attention -> d_out
#define QB 8
#define TM 64
__global__ __launch_bounds__(256) void k_fattn(const float* __restrict__ q,
    const float* __restrict__ k, const float* __restrict__ v,
    void* __restrict__ outp, const int* __restrict__ flag) {
  __shared__ float qs[QB][DKK];
  __shared__ float sc[QB][NN];
  __shared__ float tile[TM*66];
  __shared__ float oacc[QB][HID];
  int tid = threadIdx.x;
  int wave = tid >> 6, lane = tid & 63;
  int b = blockIdx.x >> 7;
  int n0 = (blockIdx.x & 127) * QB;
  if (tid < QB*DKK)
    qs[tid >> 5][tid & 31] = q[((long)b*NN + n0 + (tid >> 5))*DKK + (tid & 31)];
  __syncthreads();
  const float rs = 0.17677669529663687f;
  for (int m0 = 0; m0 < NN; m0 += TM) {
    for (int i = tid; i < TM*DKK; i += 256)
      tile[(i >> 5)*33 + (i & 31)] = k[((long)b*NN + m0)*DKK + i];
    __syncthreads();
    for (int tt = tid; tt < QB*TM; tt += 256) {
      int qq = tt >> 6, mm = tt & 63;
      const float* kt = &tile[mm*33];
      const float* qp = qs[qq];
      float a = 0;
#pragma unroll
      for (int e = 0; e < DKK; ++e) a += qp[e]*kt[e];
      sc[qq][m0 + mm] = a*rs;
    }
    __syncthreads();
  }
  for (int qq = wave*2; qq < wave*2 + 2; ++qq) {
    float mx = -1e30f;
    for (int mm = lane; mm < NN; mm += 64) mx = fmaxf(mx, sc[qq][mm]);
#pragma unroll
    for (int off = 32; off; off >>= 1) mx = fmaxf(mx, __shfl_xor(mx, off));
    float se = 0;
    for (int mm = lane; mm < NN; mm += 64) { float e = expf(sc[qq][mm]-mx); sc[qq][mm] = e; se += e; }
#pragma unroll
    for (int off = 32; off; off >>= 1) se += __shfl_xor(se, off);
    float inv = 1.f/se;
    for (int mm = lane; mm < NN; mm += 64) sc[qq][mm] *= inv;
  }
  for (int i = tid; i < QB*HID; i += 256) oacc[i >> 6][i & 63] = 0.f;
  __syncthreads();
  for (int m0 = 0; m0 < NN; m0 += TM) {
    for (int i = tid; i < TM*HID; i += 256)
      tile[i] = v[((long)b*NN + m0)*HID + i];
    __syncthreads();
    for (int tt = tid; tt < QB*HID; tt += 256) {
      int qq = tt >> 6, hh = tt & 63;
      float a = oacc[qq][hh];
      const float* sp = &sc[qq][m0];
      for (int mm = 0; mm < TM; ++mm) a += sp[mm]*tile[mm*HID + hh];
      oacc[qq][hh] = a;
    }
    __syncthreads();
  }
  int f = *flag;
  for (int qq = wave*2; qq < wave*2 + 2; ++qq) {
    float val = oacc[qq][lane];
    long idx = ((long)(b*NN + n0 + qq))*HID + lane;
    if (f) ((float*)outp)[idx] = val;
    else   ((bf16*)outp)[idx] = __float2bfloat16(val);
  }
}

// ================================================================ launch
extern "C" void kernel_launch(void* const* d_in, const int* in_sizes, int n_in,
                              void* d_out, int out_size, void* d_ws, size_t ws_size,
                              hipStream_t stream) {
  static const int EXP[30] = {
    49152, 49152, 384, 128, 49152, 768, 16384, 256,
    524288, 8192, 524288, 256, 256, 256, 256, 256,
    8192, 8192, 16384, 524288, 8192, 524288, 256, 256,
    256, 256, 256, 4096, 4096, 8192
  };
  const size_t NEED = (size_t)(1048576 + 524288 + 524288 + 524288 + 1048576) * 4 + 64;
  bool ok = (n_in == 30) && (ws_size >= NEED) && (out_size == BB*NN*HID);
  if (ok) for (int i = 0; i < 30; ++i) ok = ok && (in_sizes[i] == EXP[i]);
  if (!ok) {
    k_zero<<<(BB*NN*HID + 255)/256, 256, 0, stream>>>((unsigned short*)d_out, BB*NN*HID);
    return;
  }

  float* z   = (float*)d_ws;             // [4,1024,4,64]
  float* enc = z   + 1048576;            // [4,1024,128]
  float* qb  = enc + 524288;             // [16,1024,32] (bf16 for gattn, fp32 for fattn)
  float* kb  = qb  + 524288;
  float* vb  = kb  + 524288;             // [16,1024,64] fp32
  int*  flag = (int*)(vb + 1048576);

  k_detect<<<1, 256, 0, stream>>>(d_in[0], flag);

  const void *i_traffic=d_in[0], *i_user=d_in[1], *i_pw=d_in[2], *i_pb=d_in[3],
    *i_mw=d_in[4], *i_mb=d_in[5], *i_ow=d_in[6], *i_ob=d_in[7], *i_f1w=d_in[8],
    *i_f1b=d_in[9], *i_f2w=d_in[10], *i_f2b=d_in[11], *i_l1g=d_in[12],
    *i_l1b=d_in[13], *i_l2g=d_in[14], *i_l2b=d_in[15], *i_gwq=d_in[16],
    *i_gwk=d_in[17], *i_gwv=d_in[18], *i_gf1w=d_in[19], *i_gf1b=d_in[20],
    *i_gf2w=d_in[21], *i_gf2b=d_in[22], *i_gl1g=d_in[23], *i_gl1b=d_in[24],
    *i_gl2g=d_in[25], *i_gl2b=d_in[26], *i_cwq=d_in[27], *i_cwk=d_in[28],
    *i_cwv=d_in[29];

  const int FFG = BB*NN*SEGN/FRW;        // 1024 blocks

  for (int s = 0; s < 2; ++s) {
    const void* x = s ? i_user : i_traffic;
    k_patch<<<BB*NN, 256, 0, stream>>>(x, i_pw, (long)s*HID*SEGL, i_pb, (long)s*HID, z, flag);
    for (int i = 0; i < 2; ++i) {
      long si = s*2 + i;
      k_tattn<<<BB*NN, 64, 0, stream>>>(z,
          i_mw, si*3*HID*HID, i_mb, si*3*HID, i_ow, si*HID*HID, i_ob, si*HID,
          i_l1g, si*HID, i_l1b, si*HID, flag);
      k_ffmfma<<<FFG, 256, 0, stream>>>(z,
          i_f1w, si*FFD*HID, i_f1b, si*FFD, i_f2w, si*HID*FFD, i_f2b, si*HID,
          i_l2g, si*HID, i_l2b, si*HID, flag);
      k_gqkv<<<16*NN, 128, 0, stream>>>(z,
          i_gwq, si*DKK*HID, i_gwk, si*DKK*HID, i_gwv, si*HID*HID,
          (unsigned short*)qb, (unsigned short*)kb, vb, flag);
      k_gattn<<<16*16, 256, 0, stream>>>(z,
          (const unsigned short*)qb, (const unsigned short*)kb, vb,
          i_gl1g, si*HID, i_gl1b, si*HID, flag);
      k_ffmfma<<<FFG, 256, 0, stream>>>(z,
          i_gf1w, si*FFD*HID, i_gf1b, si*FFD, i_gf2w, si*HID*FFD, i_gf2b, si*HID,
          i_gl2g, si*HID, i_gl2b, si*HID, flag);
    }
    k_pool<<<BB*NN, 64, 0, stream>>>(z, enc, s);
  }
  k_fqkv<<<BB*NN, 128, 0, stream>>>(enc, i_cwq, i_cwk, i_cwv, qb, kb, vb, flag);
  k_fattn<<<BB*(NN/QB), 256, 0, stream>>>(qb, kb, vb, d_out, flag);
}

// Round 8
// 1448.410 us; speedup vs baseline: 1.4073x; 1.4073x over previous
//
#include <hip/hip_runtime.h>
#include <hip/hip_bf16.h>
#include <math.h>

// Problem constants
#define BB 4
#define SEQL 12
#define NN 1024
#define SEGL 3
#define SEGN 4
#define HID 64
#define FFD 2048
#define DKK 32
#define NHH 8
#define HDD 8

using bf16 = __hip_bfloat16;
__device__ __forceinline__ float b2f(bf16 v) { return __bfloat162float(v); }

typedef __attribute__((ext_vector_type(8))) short s8v;   // 8 bf16 (4 VGPRs)
typedef __attribute__((ext_vector_type(4))) float f4v;   // MFMA C/D
typedef __attribute__((ext_vector_type(4))) unsigned short u4v;

__device__ __forceinline__ unsigned short f2b(float f) {
  bf16 h = __float2bfloat16(f);
  unsigned short u; __builtin_memcpy(&u, &h, 2); return u;
}
__device__ __forceinline__ float us2f(unsigned short u) {
  unsigned int e = ((unsigned int)u) << 16;
  float f; __builtin_memcpy(&f, &e, 4); return f;
}

// dtype-templated loads: F=1 fp32 storage, F=0 bf16 storage
template <int F>
__device__ __forceinline__ float ldw(const void* p, long i) {
  if (F) return ((const float*)p)[i];
  return b2f(((const bf16*)p)[i]);
}
template <int F>
__device__ __forceinline__ s8v ldfrag(const void* p, long elemOff) {
  if (F) {
    const float* fp = (const float*)p + elemOff;
    f4v u = *(const f4v*)fp, v = *(const f4v*)(fp + 4);
    s8v t;
    t[0]=f2b(u[0]); t[1]=f2b(u[1]); t[2]=f2b(u[2]); t[3]=f2b(u[3]);
    t[4]=f2b(v[0]); t[5]=f2b(v[1]); t[6]=f2b(v[2]); t[7]=f2b(v[3]);
    return t;
  }
  return *(const s8v*)((const unsigned short*)p + elemOff);
}
template <int F>
__device__ __forceinline__ f4v ldb4(const void* p, long i) {  // 4 consecutive vals
  if (F) return *(const f4v*)((const float*)p + i);
  u4v u = *(const u4v*)((const unsigned short*)p + i);
  f4v r; r[0]=us2f(u[0]); r[1]=us2f(u[1]); r[2]=us2f(u[2]); r[3]=us2f(u[3]);
  return r;
}

// ---------------------------------------------------------------- zero-fill d_out (guard path)
__global__ void k_zero(unsigned short* __restrict__ o, int n) {
  int i = blockIdx.x * 256 + threadIdx.x;
  if (i < n) o[i] = 0;
}

// ---------------------------------------------------------------- detect dtype
__global__ void k_detect(const void* __restrict__ x0, int* __restrict__ flag) {
  int t = threadIdx.x;
  int bad = 0;
  const bf16* p = (const bf16*)x0;
  for (int i = t; i < 512; i += 256) {
    float a = fabsf(b2f(p[i]));
    if (!(a < 1e4f) || (a != 0.f && a < 1e-4f)) bad = 1;
  }
  __shared__ int tot;
  if (t == 0) tot = 0;
  __syncthreads();
  unsigned long long m = __ballot(bad);
  if ((t & 63) == 0) atomicAdd(&tot, __popcll(m));
  __syncthreads();
  if (t == 0) *flag = (tot > 64) ? 1 : 0;   // 1 = fp32 storage, 0 = bf16
}

// ---------------------------------------------------------------- patch embed
template <int F>
__device__ __forceinline__ void patch_body(const void* __restrict__ x,
    const void* __restrict__ pw, long opw, const void* __restrict__ pb, long opb,
    float* __restrict__ z) {
  int b = blockIdx.x >> 10, n = blockIdx.x & 1023;
  int g = threadIdx.x >> 6, h = threadIdx.x & 63;
  float acc = ldw<F>(pb, opb + h);
#pragma unroll
  for (int l = 0; l < SEGL; ++l)
    acc += ldw<F>(x, (long)(b*SEQL + g*SEGL + l)*NN + n) * ldw<F>(pw, opw + h*SEGL + l);
  int i2 = h >> 1;
  float dv = expf((float)(2*i2) * (-logf(10000.f) / (float)HID));
  float ang = (float)g * dv;
  acc += (h & 1) ? cosf(ang) : sinf(ang);
  z[((long)(b*NN + n)*SEGN + g)*HID + h] = acc;
}
__global__ __launch_bounds__(256) void k_patch(const void* __restrict__ x,
    const void* __restrict__ pw, long opw, const void* __restrict__ pb, long opb,
    float* __restrict__ z, const int* __restrict__ flag) {
  if (*flag) patch_body<1>(x, pw, opw, pb, opb, z);
  else       patch_body<0>(x, pw, opw, pb, opb, z);
}

// ---------------------------------------------------------------- temporal MHA + LN1
struct TattnS {
  float xr[SEGN][HID];
  float qkv[SEGN][3*HID];
  float ao[SEGN][HID];
  float mst[SEGN][2];
};
template <int F>
__device__ __forceinline__ void tattn_body(float* __restrict__ z,
    const void* __restrict__ W, long oW, const void* __restrict__ bqkv, long obq,
    const void* __restrict__ WO, long oWO, const void* __restrict__ bo, long obo,
    const void* __restrict__ g1, long og1, const void* __restrict__ b1, long ob1,
    TattnS& sm) {
  int h = threadIdx.x;
  float* zp = z + (long)blockIdx.x * SEGN * HID;
#pragma unroll
  for (int g = 0; g < SEGN; ++g) sm.xr[g][h] = zp[g*HID + h];
  __syncthreads();
#pragma unroll
  for (int j = 0; j < 3; ++j) {
    int c = j*HID + h;
    long wr = oW + (long)c*HID;
    float a0=0,a1=0,a2=0,a3=0;
    for (int k = 0; k < HID; ++k) {
      float w = ldw<F>(W, wr + k);
      a0 += sm.xr[0][k]*w; a1 += sm.xr[1][k]*w; a2 += sm.xr[2][k]*w; a3 += sm.xr[3][k]*w;
    }
    float bb = ldw<F>(bqkv, obq + c);
    sm.qkv[0][c]=a0+bb; sm.qkv[1][c]=a1+bb; sm.qkv[2][c]=a2+bb; sm.qkv[3][c]=a3+bb;
  }
  __syncthreads();
  if (h < NHH*SEGN) {
    int head = h >> 2, qt = h & 3;
    const float scale = 0.3535533905932738f;   // 1/sqrt(8)
    float s[SEGN]; float mx = -1e30f;
#pragma unroll
    for (int kt = 0; kt < SEGN; ++kt) {
      float d = 0;
#pragma unroll
      for (int e = 0; e < HDD; ++e) d += sm.qkv[qt][head*HDD+e]*sm.qkv[kt][HID+head*HDD+e];
      s[kt] = d*scale; mx = fmaxf(mx, s[kt]);
    }
    float se = 0;
#pragma unroll
    for (int kt = 0; kt < SEGN; ++kt) { s[kt] = expf(s[kt]-mx); se += s[kt]; }
    float inv = 1.f/se;
#pragma unroll
    for (int e = 0; e < HDD; ++e) {
      float o = 0;
#pragma unroll
      for (int kt = 0; kt < SEGN; ++kt) o += s[kt]*sm.qkv[kt][2*HID+head*HDD+e];
      sm.ao[qt][head*HDD+e] = o*inv;
    }
  }
  __syncthreads();
  float y[SEGN];
  {
    long wr = oWO + (long)h*HID;
    float bb = ldw<F>(bo, obo + h);
#pragma unroll
    for (int g = 0; g < SEGN; ++g) {
      float a = bb;
      for (int k = 0; k < HID; ++k) a += sm.ao[g][k]*ldw<F>(WO, wr + k);
      y[g] = sm.xr[g][h] + a;    // residual
    }
  }
  __syncthreads();
#pragma unroll
  for (int g = 0; g < SEGN; ++g) sm.xr[g][h] = y[g];
  __syncthreads();
  if (h < SEGN) {
    float m = 0;
    for (int k = 0; k < HID; ++k) m += sm.xr[h][k];
    m *= (1.f/HID);
    float v = 0;
    for (int k = 0; k < HID; ++k) { float d = sm.xr[h][k]-m; v += d*d; }
    sm.mst[h][0] = m; sm.mst[h][1] = rsqrtf(v*(1.f/HID) + 1e-5f);
  }
  __syncthreads();
  float gg = ldw<F>(g1, og1 + h), bb2 = ldw<F>(b1, ob1 + h);
#pragma unroll
  for (int g = 0; g < SEGN; ++g)
    zp[g*HID + h] = (y[g]-sm.mst[g][0])*sm.mst[g][1]*gg + bb2;
}
__global__ __launch_bounds__(64) void k_tattn(float* __restrict__ z,
    const void* W, long oW, const void* bqkv, long obq,
    const void* WO, long oWO, const void* bo, long obo,
    const void* g1, long og1, const void* b1, long ob1,
    const int* __restrict__ flag) {
  __shared__ TattnS sm;
  if (*flag) tattn_body<1>(z, W, oW, bqkv, obq, WO, oWO, bo, obo, g1, og1, b1, ob1, sm);
  else       tattn_body<0>(z, W, oW, bqkv, obq, WO, oWO, bo, obo, g1, og1, b1, ob1, sm);
}

// ---------------------------------------------------------------- FF via MFMA bf16 (v4)
// 64 rows/block (grid 256). Wave w: 4 row-tiles x hidden slice [w*512,(w+1)*512),
// chunks of 64 hidden. Each W1/W2 fragment feeds 4 MFMAs (1:4 load:MFMA).
// Zero barriers in K-loop (private per-wave hc). Epilogue: staged 2-region
// cross-wave reduction (3 barriers) aliased over the dead hc space.
#define FRW 64
template <int F>
__device__ __forceinline__ void ffmfma_body(float* __restrict__ x,
    const void* __restrict__ W1, long o1, const void* __restrict__ B1, long ob1,
    const void* __restrict__ W2, long o2, const void* __restrict__ B2, long ob2,
    const void* __restrict__ G, long og, const void* __restrict__ Bt, long obt,
    char* ldsbuf) {
  int tid = threadIdx.x;
  int w = tid >> 6, lane = tid & 63;
  int col = lane & 15, quad = lane >> 4;
  long r0 = (long)blockIdx.x * FRW;
  unsigned short* hcw = (unsigned short*)(ldsbuf + w*9216);  // [64 xrow][72] shorts

  // X B-fragments: bx[rt][ks], rows r0 + rt*16 + col
  s8v bx[4][2];
#pragma unroll
  for (int rt = 0; rt < 4; ++rt) {
    const float* xr = x + (r0 + rt*16 + col) * HID;
#pragma unroll
    for (int ks = 0; ks < 2; ++ks) {
      const float* p = xr + ks*32 + quad*8;
      f4v u = *(const f4v*)p, v = *(const f4v*)(p + 4);
      s8v t;
      t[0]=f2b(u[0]); t[1]=f2b(u[1]); t[2]=f2b(u[2]); t[3]=f2b(u[3]);
      t[4]=f2b(v[0]); t[5]=f2b(v[1]); t[6]=f2b(v[2]); t[7]=f2b(v[3]);
      bx[rt][ks] = t;
    }
  }

  f4v acc[4][4];   // [m out-tile][rt] partial Y^T
#pragma unroll
  for (int m = 0; m < 4; ++m)
#pragma unroll
    for (int rt = 0; rt < 4; ++rt) acc[m][rt] = (f4v){0.f,0.f,0.f,0.f};

  const int hb0 = w * 512;
  for (int c = 0; c < 8; ++c) {
    const int hbase = hb0 + c*64;
    // ---- prefetch this chunk's W1 fragments (8 indep 16B loads)
    s8v aw1[4][2];
#pragma unroll
    for (int t = 0; t < 4; ++t)
#pragma unroll
      for (int ks = 0; ks < 2; ++ks)
        aw1[t][ks] = ldfrag<F>(W1, o1 + (long)(hbase + t*16 + col)*HID + ks*32 + quad*8);
    // ---- GEMM1: S^T tiles -> relu -> hc (b64 packed writes)
#pragma unroll
    for (int t = 0; t < 4; ++t) {
      f4v bv = ldb4<F>(B1, ob1 + hbase + t*16 + quad*4);
#pragma unroll
      for (int rt = 0; rt < 4; ++rt) {
        f4v sv = (f4v){0.f,0.f,0.f,0.f};
#pragma unroll
        for (int ks = 0; ks < 2; ++ks)
          sv = __builtin_amdgcn_mfma_f32_16x16x32_bf16(aw1[t][ks], bx[rt][ks], sv, 0, 0, 0);
        unsigned short pk[4];
#pragma unroll
        for (int r = 0; r < 4; ++r) pk[r] = f2b(fmaxf(sv[r] + bv[r], 0.f));
        *(unsigned long long*)&hcw[(rt*16 + col)*72 + t*16 + quad*4] =
          (unsigned long long)pk[0] | ((unsigned long long)pk[1] << 16) |
          ((unsigned long long)pk[2] << 32) | ((unsigned long long)pk[3] << 48);
      }
    }
    // ---- GEMM2: acc[m][rt] += W2 @ Hc^T over this chunk
#pragma unroll
    for (int ks2 = 0; ks2 < 2; ++ks2) {
      s8v bh[4];
#pragma unroll
      for (int rt = 0; rt < 4; ++rt)
        bh[rt] = *(const s8v*)&hcw[(rt*16 + col)*72 + ks2*32 + quad*8];
#pragma unroll
      for (int m = 0; m < 4; ++m) {
        s8v aw2 = ldfrag<F>(W2, o2 + (long)(m*16 + col)*FFD + hbase + ks2*32 + quad*8);
#pragma unroll
        for (int rt = 0; rt < 4; ++rt)
          acc[m][rt] = __builtin_amdgcn_mfma_f32_16x16x32_bf16(aw2, bh[rt], acc[m][rt], 0, 0, 0);
      }
    }
  }

  // ---- epilogue: staged cross-wave reduction in 2 LDS regions (alias hc)
  float* red0 = (float*)ldsbuf;               // [64][68]
  float* red1 = (float*)(ldsbuf + 17408);
  __syncthreads();                            // all hc reads done
  if (w < 2) {
    float* rg = w ? red1 : red0;
#pragma unroll
    for (int m = 0; m < 4; ++m)
#pragma unroll
      for (int rt = 0; rt < 4; ++rt)
        *(f4v*)&rg[(rt*16 + col)*68 + m*16 + quad*4] = acc[m][rt];
  }
  __syncthreads();
  if (w >= 2) {
    float* rg = (w == 3) ? red1 : red0;
#pragma unroll
    for (int m = 0; m < 4; ++m)
#pragma unroll
      for (int rt = 0; rt < 4; ++rt) {
        float* pp = &rg[(rt*16 + col)*68 + m*16 + quad*4];
        f4v old = *(f4v*)pp;
        *(f4v*)pp = old + acc[m][rt];
      }
  }
  __syncthreads();
  // ---- final: wave w owns rows w*16..w*16+15; bias + residual + LN
  float gg = ldw<F>(G, og + lane), bbt = ldw<F>(Bt, obt + lane);
  float b2v = ldw<F>(B2, ob2 + lane);
#pragma unroll
  for (int rr = 0; rr < 16; ++rr) {
    int rl = w*16 + rr;
    long grow = r0 + rl;
    float val = red0[rl*68 + lane] + red1[rl*68 + lane] + b2v + x[grow*HID + lane];
    float s = val;
#pragma unroll
    for (int off = 32; off; off >>= 1) s += __shfl_xor(s, off);
    float m = s * (1.f/HID);
    float d = val - m;
    float sq = d*d;
#pragma unroll
    for (int off = 32; off; off >>= 1) sq += __shfl_xor(sq, off);
    float rv = rsqrtf(sq*(1.f/HID) + 1e-5f);
    x[grow*HID + lane] = d*rv*gg + bbt;
  }
}
__global__ __launch_bounds__(256) void k_ffmfma(float* __restrict__ x,
    const void* W1, long o1, const void* B1, long ob1,
    const void* W2, long o2, const void* B2, long ob2,
    const void* G, long og, const void* Bt, long obt,
    const int* __restrict__ flag) {
  __shared__ __attribute__((aligned(16))) char ldsbuf[4*9216];
  if (*flag) ffmfma_body<1>(x, W1, o1, B1, ob1, W2, o2, B2, ob2, G, og, Bt, obt, ldsbuf);
  else       ffmfma_body<0>(x, W1, o1, B1, ob1, W2, o2, B2, ob2, G, og, Bt, obt, ldsbuf);
}

// ---------------------------------------------------------------- graph qkv proj
template <int F>
__device__ __forceinline__ void gqkv_body(const float* __restrict__ z,
    const void* __restrict__ wq, long oq, const void* __restrict__ wk, long ok,
    const void* __restrict__ wv, long ov,
    unsigned short* __restrict__ q, unsigned short* __restrict__ k,
    float* __restrict__ v, float* xs) {
  int bg = blockIdx.x >> 10, n = blockIdx.x & 1023;
  int b = bg >> 2, g = bg & 3;
  const float* zp = z + ((long)(b*NN + n)*SEGN + g)*HID;
  int t = threadIdx.x;
  if (t < HID) xs[t] = zp[t];
  __syncthreads();
  long r = (long)bg*NN + n;
  if (t < 32) {
    long wr = oq + (long)t*HID; float a = 0;
    for (int e = 0; e < HID; ++e) a += xs[e]*ldw<F>(wq, wr + e);
    q[r*DKK + t] = f2b(a);
  } else if (t < 64) {
    long wr = ok + (long)(t-32)*HID; float a = 0;
    for (int e = 0; e < HID; ++e) a += xs[e]*ldw<F>(wk, wr + e);
    k[r*DKK + (t-32)] = f2b(a);
  } else {
    long wr = ov + (long)(t-64)*HID; float a = 0;
    for (int e = 0; e < HID; ++e) a += xs[e]*ldw<F>(wv, wr + e);
    v[r*HID + (t-64)] = a;
  }
}
__global__ __launch_bounds__(128) void k_gqkv(const float* __restrict__ z,
    const void* wq, long oq, const void* wk, long ok, const void* wv, long ov,
    unsigned short* q, unsigned short* k, float* v, const int* __restrict__ flag) {
  __shared__ float xs[HID];
  if (*flag) gqkv_body<1>(z, wq, oq, wk, ok, wv, ov, q, k, v, xs);
  else       gqkv_body<0>(z, wq, oq, wk, ok, wv, ov, q, k, v, xs);
}

// ---------------------------------------------------------------- graph attention (flash-MFMA)
__global__ __launch_bounds__(256) void k_gattn(float* __restrict__ z,
    const unsigned short* __restrict__ qb, const unsigned short* __restrict__ kb,
    const float* __restrict__ vb,
    const void* __restrict__ g1, long og1, const void* __restrict__ b1, long ob1,
    const int* __restrict__ flag) {
  int f = *flag;
  __shared__ unsigned short vt[64][72];   // [vdim][key]
  __shared__ unsigned short pl[64][72];   // [q_local][key]
  __shared__ float ob[64][66];
  int tid = threadIdx.x;
  int wv = tid >> 6, lane = tid & 63;
  int col = lane & 15, quad = lane >> 4;
  int bg = blockIdx.x >> 4;
  int n0 = (blockIdx.x & 15) * 64;
  long gbase = (long)bg * NN;

  s8v aq = *(const s8v*)(qb + (gbase + n0 + wv*16 + col)*DKK + quad*8);

  f4v acc[4];
#pragma unroll
  for (int t = 0; t < 4; ++t) acc[t] = (f4v){0.f,0.f,0.f,0.f};
  float mrow[4] = {-1e30f,-1e30f,-1e30f,-1e30f};
  float lrow[4] = {0.f,0.f,0.f,0.f};
  const float rs = 0.17677669529663687f;   // 1/sqrt(32)

  int kp = (tid & 31) * 2, dg = tid >> 5;

  for (int c0 = 0; c0 < NN; c0 += 64) {
    __syncthreads();
    {
      const float* vr0 = vb + (gbase + c0 + kp)*HID + dg*8;
      const float* vr1 = vr0 + HID;
      f4v u0 = *(const f4v*)vr0, u1 = *(const f4v*)(vr0 + 4);
      f4v w0 = *(const f4v*)vr1, w1 = *(const f4v*)(vr1 + 4);
#pragma unroll
      for (int i = 0; i < 4; ++i) {
        unsigned int p0 = (unsigned int)f2b(u0[i]) | ((unsigned int)f2b(w0[i]) << 16);
        unsigned int p1 = (unsigned int)f2b(u1[i]) | ((unsigned int)f2b(w1[i]) << 16);
        *(unsigned int*)&vt[dg*8 + i][kp] = p0;
        *(unsigned int*)&vt[dg*8 + 4 + i][kp] = p1;
      }
    }
    f4v s[4];
#pragma unroll
    for (int nt = 0; nt < 4; ++nt) {
      s8v bk = *(const s8v*)(kb + (gbase + c0 + nt*16 + col)*DKK + quad*8);
      s[nt] = __builtin_amdgcn_mfma_f32_16x16x32_bf16(aq, bk,
                (f4v){0.f,0.f,0.f,0.f}, 0, 0, 0);
    }
#pragma unroll
    for (int r = 0; r < 4; ++r) {
      float s0 = s[0][r]*rs, s1 = s[1][r]*rs, s2 = s[2][r]*rs, s3 = s[3][r]*rs;
      float mc = fmaxf(fmaxf(s0, s1), fmaxf(s2, s3));
#pragma unroll
      for (int off = 1; off < 16; off <<= 1) mc = fmaxf(mc, __shfl_xor(mc, off));
      float mn = fmaxf(mrow[r], mc);
      float al = expf(mrow[r] - mn);
      mrow[r] = mn;
      float p0 = expf(s0 - mn), p1 = expf(s1 - mn), p2 = expf(s2 - mn), p3 = expf(s3 - mn);
      float su = p0 + p1 + p2 + p3;
#pragma unroll
      for (int off = 1; off < 16; off <<= 1) su += __shfl_xor(su, off);
      lrow[r] = lrow[r]*al + su;
#pragma unroll
      for (int t = 0; t < 4; ++t) acc[t][r] *= al;
      int row = wv*16 + quad*4 + r;
      pl[row][col]      = f2b(p0);
      pl[row][16 + col] = f2b(p1);
      pl[row][32 + col] = f2b(p2);
      pl[row][48 + col] = f2b(p3);
    }
    __syncthreads();
#pragma unroll
    for (int ks = 0; ks < 2; ++ks) {
      s8v ap = *(const s8v*)&pl[wv*16 + col][ks*32 + quad*8];
#pragma unroll
      for (int nt = 0; nt < 4; ++nt) {
        s8v bv = *(const s8v*)&vt[nt*16 + col][ks*32 + quad*8];
        acc[nt] = __builtin_amdgcn_mfma_f32_16x16x32_bf16(ap, bv, acc[nt], 0, 0, 0);
      }
    }
  }

  float il[4];
#pragma unroll
  for (int r = 0; r < 4; ++r) il[r] = 1.f / lrow[r];
#pragma unroll
  for (int t = 0; t < 4; ++t) {
    int row = wv*16 + quad*4;
#pragma unroll
    for (int r = 0; r < 4; ++r)
      ob[row + r][t*16 + col] = acc[t][r] * il[r];
  }
  __syncthreads();
  int b = bg >> 2, g = bg & 3;
  float gg = f ? ((const float*)g1)[og1 + lane] : b2f(((const bf16*)g1)[og1 + lane]);
  float bb = f ? ((const float*)b1)[ob1 + lane] : b2f(((const bf16*)b1)[ob1 + lane]);
#pragma unroll
  for (int rr = 0; rr < 16; ++rr) {
    int rl = wv*16 + rr;
    int n = n0 + rl;
    float val = ob[rl][lane];
    float s = val;
#pragma unroll
    for (int off = 32; off; off >>= 1) s += __shfl_xor(s, off);
    float m = s*(1.f/HID);
    float d = val - m, sq = d*d;
#pragma unroll
    for (int off = 32; off; off >>= 1) sq += __shfl_xor(sq, off);
    float r = rsqrtf(sq*(1.f/HID) + 1e-5f);
    float* zp = z + ((long)(b*NN + n)*SEGN + g)*HID;
    zp[lane] = d*r*gg + bb + zp[lane];   // LN(att) + x
  }
}

// ---------------------------------------------------------------- pool over segments
__global__ __launch_bounds__(64) void k_pool(const float* __restrict__ z,
    float* __restrict__ enc, int s) {
  int b = blockIdx.x >> 10, n = blockIdx.x & 1023, h = threadIdx.x;
  const float* zp = z + (long)(b*NN + n)*SEGN*HID;
  float a = 0;
#pragma unroll
  for (int g = 0; g < SEGN; ++g) a += zp[g*HID + h];
  enc[(long)(b*NN + n)*(2*HID) + s*HID + h] = a*0.25f;
}

// ---------------------------------------------------------------- final qkv proj (in_dim=128)
template <int F>
__device__ __forceinline__ void fqkv_body(const float* __restrict__ enc,
    const void* __restrict__ wq, const void* __restrict__ wk,
    const void* __restrict__ wv,
    float* __restrict__ q, float* __restrict__ k, float* __restrict__ v,
    float* xs) {
  long r = blockIdx.x;
  int t = threadIdx.x;
  xs[t] = enc[r*128 + t];
  __syncthreads();
  if (t < 32) {
    long wr = (long)t*128; float a = 0;
    for (int e = 0; e < 128; ++e) a += xs[e]*ldw<F>(wq, wr + e);
    q[r*DKK + t] = a;
  } else if (t < 64) {
    long wr = (long)(t-32)*128; float a = 0;
    for (int e = 0; e < 128; ++e) a += xs[e]*ldw<F>(wk, wr + e);
    k[r*DKK + (t-32)] = a;
  } else {
    long wr = (long)(t-64)*128; float a = 0;
    for (int e = 0; e < 128; ++e) a += xs[e]*ldw<F>(wv, wr + e);
    v[r*HID + (t-64)] = a;
  }
}
__global__ __launch_bounds__(128) void k_fqkv(const float* __restrict__ enc,
    const void* wq, const void* wk, const void* wv,
    float* q, float* k, float* v, const int* __restrict__ flag) {
  __shared__ float xs[2*HID];
  if (*flag) fqkv_body<1>(enc, wq, wk, wv, q, k, v, xs);
  else       fqkv_body<0>(enc, wq, wk, wv, q, k, v, xs);
}

// ---------------------------------------------------------------- final attention -> d_out
#define QB 8
#define TM 64
__global__ __launch_bounds__(256) void k_fattn(const float* __restrict__ q,
    const float* __restrict__ k, const float* __restrict__ v,
    void* __restrict__ outp, const int* __restrict__ flag) {
  __shared__ float qs[QB][DKK];
  __shared__ float sc[QB][NN];
  __shared__ float tile[TM*66];
  __shared__ float oacc[QB][HID];
  int tid = threadIdx.x;
  int wave = tid >> 6, lane = tid & 63;
  int b = blockIdx.x >> 7;
  int n0 = (blockIdx.x & 127) * QB;
  if (tid < QB*DKK)
    qs[tid >> 5][tid & 31] = q[((long)b*NN + n0 + (tid >> 5))*DKK + (tid & 31)];
  __syncthreads();
  const float rs = 0.17677669529663687f;
  for (int m0 = 0; m0 < NN; m0 += TM) {
    for (int i = tid; i < TM*DKK; i += 256)
      tile[(i >> 5)*33 + (i & 31)] = k[((long)b*NN + m0)*DKK + i];
    __syncthreads();
    for (int tt = tid; tt < QB*TM; tt += 256) {
      int qq = tt >> 6, mm = tt & 63;
      const float* kt = &tile[mm*33];
      const float* qp = qs[qq];
      float a = 0;
#pragma unroll
      for (int e = 0; e < DKK; ++e) a += qp[e]*kt[e];
      sc[qq][m0 + mm] = a*rs;
    }
    __syncthreads();
  }
  for (int qq = wave*2; qq < wave*2 + 2; ++qq) {
    float mx = -1e30f;
    for (int mm = lane; mm < NN; mm += 64) mx = fmaxf(mx, sc[qq][mm]);
#pragma unroll
    for (int off = 32; off; off >>= 1) mx = fmaxf(mx, __shfl_xor(mx, off));
    float se = 0;
    for (int mm = lane; mm < NN; mm += 64) { float e = expf(sc[qq][mm]-mx); sc[qq][mm] = e; se += e; }
#pragma unroll
    for (int off = 32; off; off >>= 1) se += __shfl_xor(se, off);
    float inv = 1.f/se;
    for (int mm = lane; mm < NN; mm += 64) sc[qq][mm] *= inv;
  }
  for (int i = tid; i < QB*HID; i += 256) oacc[i >> 6][i & 63] = 0.f;
  __syncthreads();
  for (int m0 = 0; m0 < NN; m0 += TM) {
    for (int i = tid; i < TM*HID; i += 256)
      tile[i] = v[((long)b*NN + m0)*HID + i];
    __syncthreads();
    for (int tt = tid; tt < QB*HID; tt += 256) {
      int qq = tt >> 6, hh = tt & 63;
      float a = oacc[qq][hh];
      const float* sp = &sc[qq][m0];
      for (int mm = 0; mm < TM; ++mm) a += sp[mm]*tile[mm*HID + hh];
      oacc[qq][hh] = a;
    }
    __syncthreads();
  }
  int f = *flag;
  for (int qq = wave*2; qq < wave*2 + 2; ++qq) {
    float val = oacc[qq][lane];
    long idx = ((long)(b*NN + n0 + qq))*HID + lane;
    if (f) ((float*)outp)[idx] = val;
    else   ((bf16*)outp)[idx] = __float2bfloat16(val);
  }
}

// ================================================================ launch
extern "C" void kernel_launch(void* const* d_in, const int* in_sizes, int n_in,
                              void* d_out, int out_size, void* d_ws, size_t ws_size,
                              hipStream_t stream) {
  static const int EXP[30] = {
    49152, 49152, 384, 128, 49152, 768, 16384, 256,
    524288, 8192, 524288, 256, 256, 256, 256, 256,
    8192, 8192, 16384, 524288, 8192, 524288, 256, 256,
    256, 256, 256, 4096, 4096, 8192
  };
  const size_t NEED = (size_t)(1048576 + 524288 + 524288 + 524288 + 1048576) * 4 + 64;
  bool ok = (n_in == 30) && (ws_size >= NEED) && (out_size == BB*NN*HID);
  if (ok) for (int i = 0; i < 30; ++i) ok = ok && (in_sizes[i] == EXP[i]);
  if (!ok) {
    k_zero<<<(BB*NN*HID + 255)/256, 256, 0, stream>>>((unsigned short*)d_out, BB*NN*HID);
    return;
  }

  float* z   = (float*)d_ws;             // [4,1024,4,64]
  float* enc = z   + 1048576;            // [4,1024,128]
  float* qb  = enc + 524288;             // [16,1024,32] (bf16 for gattn, fp32 for fattn)
  float* kb  = qb  + 524288;
  float* vb  = kb  + 524288;             // [16,1024,64] fp32
  int*  flag = (int*)(vb + 1048576);

  k_detect<<<1, 256, 0, stream>>>(d_in[0], flag);

  const void *i_traffic=d_in[0], *i_user=d_in[1], *i_pw=d_in[2], *i_pb=d_in[3],
    *i_mw=d_in[4], *i_mb=d_in[5], *i_ow=d_in[6], *i_ob=d_in[7], *i_f1w=d_in[8],
    *i_f1b=d_in[9], *i_f2w=d_in[10], *i_f2b=d_in[11], *i_l1g=d_in[12],
    *i_l1b=d_in[13], *i_l2g=d_in[14], *i_l2b=d_in[15], *i_gwq=d_in[16],
    *i_gwk=d_in[17], *i_gwv=d_in[18], *i_gf1w=d_in[19], *i_gf1b=d_in[20],
    *i_gf2w=d_in[21], *i_gf2b=d_in[22], *i_gl1g=d_in[23], *i_gl1b=d_in[24],
    *i_gl2g=d_in[25], *i_gl2b=d_in[26], *i_cwq=d_in[27], *i_cwk=d_in[28],
    *i_cwv=d_in[29];

  const int FFG = BB*NN*SEGN/FRW;        // 256 blocks

  for (int s = 0; s < 2; ++s) {
    const void* x = s ? i_user : i_traffic;
    k_patch<<<BB*NN, 256, 0, stream>>>(x, i_pw, (long)s*HID*SEGL, i_pb, (long)s*HID, z, flag);
    for (int i = 0; i < 2; ++i) {
      long si = s*2 + i;
      k_tattn<<<BB*NN, 64, 0, stream>>>(z,
          i_mw, si*3*HID*HID, i_mb, si*3*HID, i_ow, si*HID*HID, i_ob, si*HID,
          i_l1g, si*HID, i_l1b, si*HID, flag);
      k_ffmfma<<<FFG, 256, 0, stream>>>(z,
          i_f1w, si*FFD*HID, i_f1b, si*FFD, i_f2w, si*HID*FFD, i_f2b, si*HID,
          i_l2g, si*HID, i_l2b, si*HID, flag);
      k_gqkv<<<16*NN, 128, 0, stream>>>(z,
          i_gwq, si*DKK*HID, i_gwk, si*DKK*HID, i_gwv, si*HID*HID,
          (unsigned short*)qb, (unsigned short*)kb, vb, flag);
      k_gattn<<<16*16, 256, 0, stream>>>(z,
          (const unsigned short*)qb, (const unsigned short*)kb, vb,
          i_gl1g, si*HID, i_gl1b, si*HID, flag);
      k_ffmfma<<<FFG, 256, 0, stream>>>(z,
          i_gf1w, si*FFD*HID, i_gf1b, si*FFD, i_gf2w, si*HID*FFD, i_gf2b, si*HID,
          i_gl2g, si*HID, i_gl2b, si*HID, flag);
    }
    k_pool<<<BB*NN, 64, 0, stream>>>(z, enc, s);
  }
  k_fqkv<<<BB*NN, 128, 0, stream>>>(enc, i_cwq, i_cwk, i_cwv, qb, kb, vb, flag);
  k_fattn<<<BB*(NN/QB), 256, 0, stream>>>(qb, kb, vb, d_out, flag);
}

// Round 9
// 1249.618 us; speedup vs baseline: 1.6312x; 1.1591x over previous
//
#include <hip/hip_runtime.h>
#include <hip/hip_bf16.h>
#include <math.h>

// Problem constants
#define BB 4
#define SEQL 12
#define NN 1024
#define SEGL 3
#define SEGN 4
#define HID 64
#define FFD 2048
#define DKK 32
#define NHH 8
#define HDD 8

using bf16 = __hip_bfloat16;
__device__ __forceinline__ float b2f(bf16 v) { return __bfloat162float(v); }

typedef __attribute__((ext_vector_type(8))) short s8v;   // 8 bf16 (4 VGPRs)
typedef __attribute__((ext_vector_type(4))) float f4v;   // MFMA C/D
typedef __attribute__((ext_vector_type(4))) unsigned short u4v;

__device__ __forceinline__ unsigned short f2b(float f) {
  bf16 h = __float2bfloat16(f);
  unsigned short u; __builtin_memcpy(&u, &h, 2); return u;
}
__device__ __forceinline__ float us2f(unsigned short u) {
  unsigned int e = ((unsigned int)u) << 16;
  float f; __builtin_memcpy(&f, &e, 4); return f;
}

// dtype-templated loads: F=1 fp32 storage, F=0 bf16 storage
template <int F>
__device__ __forceinline__ float ldw(const void* p, long i) {
  if (F) return ((const float*)p)[i];
  return b2f(((const bf16*)p)[i]);
}
template <int F>
__device__ __forceinline__ s8v ldfrag(const void* p, long elemOff) {
  if (F) {
    const float* fp = (const float*)p + elemOff;
    f4v u = *(const f4v*)fp, v = *(const f4v*)(fp + 4);
    s8v t;
    t[0]=f2b(u[0]); t[1]=f2b(u[1]); t[2]=f2b(u[2]); t[3]=f2b(u[3]);
    t[4]=f2b(v[0]); t[5]=f2b(v[1]); t[6]=f2b(v[2]); t[7]=f2b(v[3]);
    return t;
  }
  return *(const s8v*)((const unsigned short*)p + elemOff);
}
template <int F>
__device__ __forceinline__ f4v ldb4(const void* p, long i) {  // 4 consecutive vals
  if (F) return *(const f4v*)((const float*)p + i);
  u4v u = *(const u4v*)((const unsigned short*)p + i);
  f4v r; r[0]=us2f(u[0]); r[1]=us2f(u[1]); r[2]=us2f(u[2]); r[3]=us2f(u[3]);
  return r;
}

// ---------------------------------------------------------------- zero-fill d_out (guard path)
__global__ void k_zero(unsigned short* __restrict__ o, int n) {
  int i = blockIdx.x * 256 + threadIdx.x;
  if (i < n) o[i] = 0;
}

// ---------------------------------------------------------------- detect dtype
__global__ void k_detect(const void* __restrict__ x0, int* __restrict__ flag) {
  int t = threadIdx.x;
  int bad = 0;
  const bf16* p = (const bf16*)x0;
  for (int i = t; i < 512; i += 256) {
    float a = fabsf(b2f(p[i]));
    if (!(a < 1e4f) || (a != 0.f && a < 1e-4f)) bad = 1;
  }
  __shared__ int tot;
  if (t == 0) tot = 0;
  __syncthreads();
  unsigned long long m = __ballot(bad);
  if ((t & 63) == 0) atomicAdd(&tot, __popcll(m));
  __syncthreads();
  if (t == 0) *flag = (tot > 64) ? 1 : 0;   // 1 = fp32 storage, 0 = bf16
}

// ---------------------------------------------------------------- patch embed
template <int F>
__device__ __forceinline__ void patch_body(const void* __restrict__ x,
    const void* __restrict__ pw, long opw, const void* __restrict__ pb, long opb,
    float* __restrict__ z) {
  int b = blockIdx.x >> 10, n = blockIdx.x & 1023;
  int g = threadIdx.x >> 6, h = threadIdx.x & 63;
  float acc = ldw<F>(pb, opb + h);
#pragma unroll
  for (int l = 0; l < SEGL; ++l)
    acc += ldw<F>(x, (long)(b*SEQL + g*SEGL + l)*NN + n) * ldw<F>(pw, opw + h*SEGL + l);
  int i2 = h >> 1;
  float dv = expf((float)(2*i2) * (-logf(10000.f) / (float)HID));
  float ang = (float)g * dv;
  acc += (h & 1) ? cosf(ang) : sinf(ang);
  z[((long)(b*NN + n)*SEGN + g)*HID + h] = acc;
}
__global__ __launch_bounds__(256) void k_patch(const void* __restrict__ x,
    const void* __restrict__ pw, long opw, const void* __restrict__ pb, long opb,
    float* __restrict__ z, const int* __restrict__ flag) {
  if (*flag) patch_body<1>(x, pw, opw, pb, opb, z);
  else       patch_body<0>(x, pw, opw, pb, opb, z);
}

// ---------------------------------------------------------------- temporal MHA + LN1 (MFMA v2)
// 64 tokens (16 groups)/block, 256 blocks, 256 threads.
// QKV: M=192 outcols (12 N-tiles, 3/wave), tokens as MFMA-B. -> bf16 LDS.
// Attention: 128 threads, one (group,head) each, 4x4 softmax in VALU.
// Out proj: MFMA (N-tile per wave) + bias; epilogue residual + LN.
#define TT 64
template <int F>
__device__ __forceinline__ void tattn_body(float* __restrict__ z,
    const void* __restrict__ W, long oW, const void* __restrict__ bq, long obq,
    const void* __restrict__ WO, long oWO, const void* __restrict__ bo, long obo,
    const void* __restrict__ g1, long og1, const void* __restrict__ b1, long ob1,
    char* lds) {
  unsigned short (*qkvs)[200] = (unsigned short(*)[200])lds;        // 25600 B
  unsigned short (*ao)[72]    = (unsigned short(*)[72])(lds + 25600); // 9216 B
  float (*yb)[68]             = (float(*)[68])(lds + 34816);          // 17408 B
  int tid = threadIdx.x;
  int w = tid >> 6, lane = tid & 63;
  int col = lane & 15, quad = lane >> 4;
  long r0 = (long)blockIdx.x * TT;

  // ---- token B-fragments from z
  s8v bx[4][2];
#pragma unroll
  for (int mt = 0; mt < 4; ++mt) {
    const float* xr = z + (r0 + mt*16 + col) * HID;
#pragma unroll
    for (int ks = 0; ks < 2; ++ks) {
      const float* p = xr + ks*32 + quad*8;
      f4v u = *(const f4v*)p, v = *(const f4v*)(p + 4);
      s8v t;
      t[0]=f2b(u[0]); t[1]=f2b(u[1]); t[2]=f2b(u[2]); t[3]=f2b(u[3]);
      t[4]=f2b(v[0]); t[5]=f2b(v[1]); t[6]=f2b(v[2]); t[7]=f2b(v[3]);
      bx[mt][ks] = t;
    }
  }
  // ---- QKV GEMM: wave w covers outcol tiles w*3..w*3+2
#pragma unroll
  for (int nt = 0; nt < 3; ++nt) {
    int cbase = (w*3 + nt) * 16;
    s8v aw[2];
#pragma unroll
    for (int ks = 0; ks < 2; ++ks)
      aw[ks] = ldfrag<F>(W, oW + (long)(cbase + col)*HID + ks*32 + quad*8);
    f4v bv = ldb4<F>(bq, obq + cbase + quad*4);
#pragma unroll
    for (int mt = 0; mt < 4; ++mt) {
      f4v sv = (f4v){0.f,0.f,0.f,0.f};
#pragma unroll
      for (int ks = 0; ks < 2; ++ks)
        sv = __builtin_amdgcn_mfma_f32_16x16x32_bf16(aw[ks], bx[mt][ks], sv, 0, 0, 0);
      unsigned short pk[4];
#pragma unroll
      for (int r = 0; r < 4; ++r) pk[r] = f2b(sv[r] + bv[r]);
      *(unsigned long long*)&qkvs[mt*16 + col][cbase + quad*4] =
        (unsigned long long)pk[0] | ((unsigned long long)pk[1] << 16) |
        ((unsigned long long)pk[2] << 32) | ((unsigned long long)pk[3] << 48);
    }
  }
  __syncthreads();
  // ---- per-(group,head) attention, threads 0..127
  if (tid < 128) {
    int gi = tid >> 3, hd = tid & 7;
    int tl = gi * 4;
    float qv[4][8], kv[4][8], vv[4][8];
#pragma unroll
    for (int t4 = 0; t4 < 4; ++t4) {
      s8v qq = *(const s8v*)&qkvs[tl + t4][hd*8];
      s8v kk = *(const s8v*)&qkvs[tl + t4][64 + hd*8];
      s8v vq = *(const s8v*)&qkvs[tl + t4][128 + hd*8];
#pragma unroll
      for (int e = 0; e < 8; ++e) {
        qv[t4][e] = us2f((unsigned short)qq[e]);
        kv[t4][e] = us2f((unsigned short)kk[e]);
        vv[t4][e] = us2f((unsigned short)vq[e]);
      }
    }
    const float sc8 = 0.3535533905932738f;   // 1/sqrt(8)
#pragma unroll
    for (int qt = 0; qt < 4; ++qt) {
      float s[4]; float mx = -1e30f;
#pragma unroll
      for (int kt = 0; kt < 4; ++kt) {
        float d = 0;
#pragma unroll
        for (int e = 0; e < 8; ++e) d += qv[qt][e]*kv[kt][e];
        s[kt] = d*sc8; mx = fmaxf(mx, s[kt]);
      }
      float se = 0;
#pragma unroll
      for (int kt = 0; kt < 4; ++kt) { s[kt] = expf(s[kt]-mx); se += s[kt]; }
      float inv = 1.f/se;
      s8v outp;
#pragma unroll
      for (int e = 0; e < 8; ++e) {
        float o = 0;
#pragma unroll
        for (int kt = 0; kt < 4; ++kt) o += s[kt]*vv[kt][e];
        outp[e] = (short)f2b(o*inv);
      }
      *(s8v*)&ao[tl + qt][hd*8] = outp;
    }
  }
  __syncthreads();
  // ---- output proj: wave w covers outcol tile w
  s8v awo[2];
#pragma unroll
  for (int ks = 0; ks < 2; ++ks)
    awo[ks] = ldfrag<F>(WO, oWO + (long)(w*16 + col)*HID + ks*32 + quad*8);
  f4v bov = ldb4<F>(bo, obo + w*16 + quad*4);
#pragma unroll
  for (int mt = 0; mt < 4; ++mt) {
    f4v ov = (f4v){0.f,0.f,0.f,0.f};
#pragma unroll
    for (int ks = 0; ks < 2; ++ks) {
      s8v bao = *(const s8v*)&ao[mt*16 + col][ks*32 + quad*8];
      ov = __builtin_amdgcn_mfma_f32_16x16x32_bf16(awo[ks], bao, ov, 0, 0, 0);
    }
    f4v yv;
#pragma unroll
    for (int r = 0; r < 4; ++r) yv[r] = ov[r] + bov[r];
    *(f4v*)&yb[mt*16 + col][w*16 + quad*4] = yv;
  }
  __syncthreads();
  // ---- residual + LN; wave w owns rows w*16..+15, lane = dim
  float gg = ldw<F>(g1, og1 + lane), bb2 = ldw<F>(b1, ob1 + lane);
#pragma unroll
  for (int rr = 0; rr < 16; ++rr) {
    int row = w*16 + rr;
    long tok = r0 + row;
    float val = yb[row][lane] + z[tok*HID + lane];
    float s = val;
#pragma unroll
    for (int off = 32; off; off >>= 1) s += __shfl_xor(s, off);
    float m = s*(1.f/HID);
    float d = val - m, sq = d*d;
#pragma unroll
    for (int off = 32; off; off >>= 1) sq += __shfl_xor(sq, off);
    float rv = rsqrtf(sq*(1.f/HID) + 1e-5f);
    z[tok*HID + lane] = d*rv*gg + bb2;
  }
}
__global__ __launch_bounds__(256) void k_tattn(float* __restrict__ z,
    const void* W, long oW, const void* bqkv, long obq,
    const void* WO, long oWO, const void* bo, long obo,
    const void* g1, long og1, const void* b1, long ob1,
    const int* __restrict__ flag) {
  __shared__ __attribute__((aligned(16))) char lds[52224];
  if (*flag) tattn_body<1>(z, W, oW, bqkv, obq, WO, oWO, bo, obo, g1, og1, b1, ob1, lds);
  else       tattn_body<0>(z, W, oW, bqkv, obq, WO, oWO, bo, obo, g1, og1, b1, ob1, lds);
}

// ---------------------------------------------------------------- FF via MFMA bf16 (v4)
#define FRW 64
template <int F>
__device__ __forceinline__ void ffmfma_body(float* __restrict__ x,
    const void* __restrict__ W1, long o1, const void* __restrict__ B1, long ob1,
    const void* __restrict__ W2, long o2, const void* __restrict__ B2, long ob2,
    const void* __restrict__ G, long og, const void* __restrict__ Bt, long obt,
    char* ldsbuf) {
  int tid = threadIdx.x;
  int w = tid >> 6, lane = tid & 63;
  int col = lane & 15, quad = lane >> 4;
  long r0 = (long)blockIdx.x * FRW;
  unsigned short* hcw = (unsigned short*)(ldsbuf + w*9216);  // [64 xrow][72] shorts

  s8v bx[4][2];
#pragma unroll
  for (int rt = 0; rt < 4; ++rt) {
    const float* xr = x + (r0 + rt*16 + col) * HID;
#pragma unroll
    for (int ks = 0; ks < 2; ++ks) {
      const float* p = xr + ks*32 + quad*8;
      f4v u = *(const f4v*)p, v = *(const f4v*)(p + 4);
      s8v t;
      t[0]=f2b(u[0]); t[1]=f2b(u[1]); t[2]=f2b(u[2]); t[3]=f2b(u[3]);
      t[4]=f2b(v[0]); t[5]=f2b(v[1]); t[6]=f2b(v[2]); t[7]=f2b(v[3]);
      bx[rt][ks] = t;
    }
  }

  f4v acc[4][4];
#pragma unroll
  for (int m = 0; m < 4; ++m)
#pragma unroll
    for (int rt = 0; rt < 4; ++rt) acc[m][rt] = (f4v){0.f,0.f,0.f,0.f};

  const int hb0 = w * 512;
  for (int c = 0; c < 8; ++c) {
    const int hbase = hb0 + c*64;
    s8v aw1[4][2];
#pragma unroll
    for (int t = 0; t < 4; ++t)
#pragma unroll
      for (int ks = 0; ks < 2; ++ks)
        aw1[t][ks] = ldfrag<F>(W1, o1 + (long)(hbase + t*16 + col)*HID + ks*32 + quad*8);
#pragma unroll
    for (int t = 0; t < 4; ++t) {
      f4v bv = ldb4<F>(B1, ob1 + hbase + t*16 + quad*4);
#pragma unroll
      for (int rt = 0; rt < 4; ++rt) {
        f4v sv = (f4v){0.f,0.f,0.f,0.f};
#pragma unroll
        for (int ks = 0; ks < 2; ++ks)
          sv = __builtin_amdgcn_mfma_f32_16x16x32_bf16(aw1[t][ks], bx[rt][ks], sv, 0, 0, 0);
        unsigned short pk[4];
#pragma unroll
        for (int r = 0; r < 4; ++r) pk[r] = f2b(fmaxf(sv[r] + bv[r], 0.f));
        *(unsigned long long*)&hcw[(rt*16 + col)*72 + t*16 + quad*4] =
          (unsigned long long)pk[0] | ((unsigned long long)pk[1] << 16) |
          ((unsigned long long)pk[2] << 32) | ((unsigned long long)pk[3] << 48);
      }
    }
#pragma unroll
    for (int ks2 = 0; ks2 < 2; ++ks2) {
      s8v bh[4];
#pragma unroll
      for (int rt = 0; rt < 4; ++rt)
        bh[rt] = *(const s8v*)&hcw[(rt*16 + col)*72 + ks2*32 + quad*8];
#pragma unroll
      for (int m = 0; m < 4; ++m) {
        s8v aw2 = ldfrag<F>(W2, o2 + (long)(m*16 + col)*FFD + hbase + ks2*32 + quad*8);
#pragma unroll
        for (int rt = 0; rt < 4; ++rt)
          acc[m][rt] = __builtin_amdgcn_mfma_f32_16x16x32_bf16(aw2, bh[rt], acc[m][rt], 0, 0, 0);
      }
    }
  }

  float* red0 = (float*)ldsbuf;               // [64][68]
  float* red1 = (float*)(ldsbuf + 17408);
  __syncthreads();
  if (w < 2) {
    float* rg = w ? red1 : red0;
#pragma unroll
    for (int m = 0; m < 4; ++m)
#pragma unroll
      for (int rt = 0; rt < 4; ++rt)
        *(f4v*)&rg[(rt*16 + col)*68 + m*16 + quad*4] = acc[m][rt];
  }
  __syncthreads();
  if (w >= 2) {
    float* rg = (w == 3) ? red1 : red0;
#pragma unroll
    for (int m = 0; m < 4; ++m)
#pragma unroll
      for (int rt = 0; rt < 4; ++rt) {
        float* pp = &rg[(rt*16 + col)*68 + m*16 + quad*4];
        f4v old = *(f4v*)pp;
        *(f4v*)pp = old + acc[m][rt];
      }
  }
  __syncthreads();
  float gg = ldw<F>(G, og + lane), bbt = ldw<F>(Bt, obt + lane);
  float b2v = ldw<F>(B2, ob2 + lane);
#pragma unroll
  for (int rr = 0; rr < 16; ++rr) {
    int rl = w*16 + rr;
    long grow = r0 + rl;
    float val = red0[rl*68 + lane] + red1[rl*68 + lane] + b2v + x[grow*HID + lane];
    float s = val;
#pragma unroll
    for (int off = 32; off; off >>= 1) s += __shfl_xor(s, off);
    float m = s * (1.f/HID);
    float d = val - m;
    float sq = d*d;
#pragma unroll
    for (int off = 32; off; off >>= 1) sq += __shfl_xor(sq, off);
    float rv = rsqrtf(sq*(1.f/HID) + 1e-5f);
    x[grow*HID + lane] = d*rv*gg + bbt;
  }
}
__global__ __launch_bounds__(256) void k_ffmfma(float* __restrict__ x,
    const void* W1, long o1, const void* B1, long ob1,
    const void* W2, long o2, const void* B2, long ob2,
    const void* G, long og, const void* Bt, long obt,
    const int* __restrict__ flag) {
  __shared__ __attribute__((aligned(16))) char ldsbuf[4*9216];
  if (*flag) ffmfma_body<1>(x, W1, o1, B1, ob1, W2, o2, B2, ob2, G, og, Bt, obt, ldsbuf);
  else       ffmfma_body<0>(x, W1, o1, B1, ob1, W2, o2, B2, ob2, G, og, Bt, obt, ldsbuf);
}

// ---------------------------------------------------------------- graph qkv proj
template <int F>
__device__ __forceinline__ void gqkv_body(const float* __restrict__ z,
    const void* __restrict__ wq, long oq, const void* __restrict__ wk, long ok,
    const void* __restrict__ wv, long ov,
    unsigned short* __restrict__ q, unsigned short* __restrict__ k,
    float* __restrict__ v, float* xs) {
  int bg = blockIdx.x >> 10, n = blockIdx.x & 1023;
  int b = bg >> 2, g = bg & 3;
  const float* zp = z + ((long)(b*NN + n)*SEGN + g)*HID;
  int t = threadIdx.x;
  if (t < HID) xs[t] = zp[t];
  __syncthreads();
  long r = (long)bg*NN + n;
  if (t < 32) {
    long wr = oq + (long)t*HID; float a = 0;
    for (int e = 0; e < HID; ++e) a += xs[e]*ldw<F>(wq, wr + e);
    q[r*DKK + t] = f2b(a);
  } else if (t < 64) {
    long wr = ok + (long)(t-32)*HID; float a = 0;
    for (int e = 0; e < HID; ++e) a += xs[e]*ldw<F>(wk, wr + e);
    k[r*DKK + (t-32)] = f2b(a);
  } else {
    long wr = ov + (long)(t-64)*HID; float a = 0;
    for (int e = 0; e < HID; ++e) a += xs[e]*ldw<F>(wv, wr + e);
    v[r*HID + (t-64)] = a;
  }
}
__global__ __launch_bounds__(128) void k_gqkv(const float* __restrict__ z,
    const void* wq, long oq, const void* wk, long ok, const void* wv, long ov,
    unsigned short* q, unsigned short* k, float* v, const int* __restrict__ flag) {
  __shared__ float xs[HID];
  if (*flag) gqkv_body<1>(z, wq, oq, wk, ok, wv, ov, q, k, v, xs);
  else       gqkv_body<0>(z, wq, oq, wk, ok, wv, ov, q, k, v, xs);
}

// ---------------------------------------------------------------- graph attention (flash-MFMA)
__global__ __launch_bounds__(256) void k_gattn(float* __restrict__ z,
    const unsigned short* __restrict__ qb, const unsigned short* __restrict__ kb,
    const float* __restrict__ vb,
    const void* __restrict__ g1, long og1, const void* __restrict__ b1, long ob1,
    const int* __restrict__ flag) {
  int f = *flag;
  __shared__ unsigned short vt[64][72];   // [vdim][key]
  __shared__ unsigned short pl[64][72];   // [q_local][key]
  __shared__ float ob[64][66];
  int tid = threadIdx.x;
  int wv = tid >> 6, lane = tid & 63;
  int col = lane & 15, quad = lane >> 4;
  int bg = blockIdx.x >> 4;
  int n0 = (blockIdx.x & 15) * 64;
  long gbase = (long)bg * NN;

  s8v aq = *(const s8v*)(qb + (gbase + n0 + wv*16 + col)*DKK + quad*8);

  f4v acc[4];
#pragma unroll
  for (int t = 0; t < 4; ++t) acc[t] = (f4v){0.f,0.f,0.f,0.f};
  float mrow[4] = {-1e30f,-1e30f,-1e30f,-1e30f};
  float lrow[4] = {0.f,0.f,0.f,0.f};
  const float rs = 0.17677669529663687f;   // 1/sqrt(32)

  int kp = (tid & 31) * 2, dg = tid >> 5;

  for (int c0 = 0; c0 < NN; c0 += 64) {
    __syncthreads();
    {
      const float* vr0 = vb + (gbase + c0 + kp)*HID + dg*8;
      const float* vr1 = vr0 + HID;
      f4v u0 = *(const f4v*)vr0, u1 = *(const f4v*)(vr0 + 4);
      f4v w0 = *(const f4v*)vr1, w1 = *(const f4v*)(vr1 + 4);
#pragma unroll
      for (int i = 0; i < 4; ++i) {
        unsigned int p0 = (unsigned int)f2b(u0[i]) | ((unsigned int)f2b(w0[i]) << 16);
        unsigned int p1 = (unsigned int)f2b(u1[i]) | ((unsigned int)f2b(w1[i]) << 16);
        *(unsigned int*)&vt[dg*8 + i][kp] = p0;
        *(unsigned int*)&vt[dg*8 + 4 + i][kp] = p1;
      }
    }
    f4v s[4];
#pragma unroll
    for (int nt = 0; nt < 4; ++nt) {
      s8v bk = *(const s8v*)(kb + (gbase + c0 + nt*16 + col)*DKK + quad*8);
      s[nt] = __builtin_amdgcn_mfma_f32_16x16x32_bf16(aq, bk,
                (f4v){0.f,0.f,0.f,0.f}, 0, 0, 0);
    }
#pragma unroll
    for (int r = 0; r < 4; ++r) {
      float s0 = s[0][r]*rs, s1 = s[1][r]*rs, s2 = s[2][r]*rs, s3 = s[3][r]*rs;
      float mc = fmaxf(fmaxf(s0, s1), fmaxf(s2, s3));
#pragma unroll
      for (int off = 1; off < 16; off <<= 1) mc = fmaxf(mc, __shfl_xor(mc, off));
      float mn = fmaxf(mrow[r], mc);
      float al = expf(mrow[r] - mn);
      mrow[r] = mn;
      float p0 = expf(s0 - mn), p1 = expf(s1 - mn), p2 = expf(s2 - mn), p3 = expf(s3 - mn);
      float su = p0 + p1 + p2 + p3;
#pragma unroll
      for (int off = 1; off < 16; off <<= 1) su += __shfl_xor(su, off);
      lrow[r] = lrow[r]*al + su;
#pragma unroll
      for (int t = 0; t < 4; ++t) acc[t][r] *= al;
      int row = wv*16 + quad*4 + r;
      pl[row][col]      = f2b(p0);
      pl[row][16 + col] = f2b(p1);
      pl[row][32 + col] = f2b(p2);
      pl[row][48 + col] = f2b(p3);
    }
    __syncthreads();
#pragma unroll
    for (int ks = 0; ks < 2; ++ks) {
      s8v ap = *(const s8v*)&pl[wv*16 + col][ks*32 + quad*8];
#pragma unroll
      for (int nt = 0; nt < 4; ++nt) {
        s8v bv = *(const s8v*)&vt[nt*16 + col][ks*32 + quad*8];
        acc[nt] = __builtin_amdgcn_mfma_f32_16x16x32_bf16(ap, bv, acc[nt], 0, 0, 0);
      }
    }
  }

  float il[4];
#pragma unroll
  for (int r = 0; r < 4; ++r) il[r] = 1.f / lrow[r];
#pragma unroll
  for (int t = 0; t < 4; ++t) {
    int row = wv*16 + quad*4;
#pragma unroll
    for (int r = 0; r < 4; ++r)
      ob[row + r][t*16 + col] = acc[t][r] * il[r];
  }
  __syncthreads();
  int b = bg >> 2, g = bg & 3;
  float gg = f ? ((const float*)g1)[og1 + lane] : b2f(((const bf16*)g1)[og1 + lane]);
  float bb = f ? ((const float*)b1)[ob1 + lane] : b2f(((const bf16*)b1)[ob1 + lane]);
#pragma unroll
  for (int rr = 0; rr < 16; ++rr) {
    int rl = wv*16 + rr;
    int n = n0 + rl;
    float val = ob[rl][lane];
    float s = val;
#pragma unroll
    for (int off = 32; off; off >>= 1) s += __shfl_xor(s, off);
    float m = s*(1.f/HID);
    float d = val - m, sq = d*d;
#pragma unroll
    for (int off = 32; off; off >>= 1) sq += __shfl_xor(sq, off);
    float r = rsqrtf(sq*(1.f/HID) + 1e-5f);
    float* zp = z + ((long)(b*NN + n)*SEGN + g)*HID;
    zp[lane] = d*r*gg + bb + zp[lane];   // LN(att) + x
  }
}

// ---------------------------------------------------------------- pool over segments
__global__ __launch_bounds__(64) void k_pool(const float* __restrict__ z,
    float* __restrict__ enc, int s) {
  int b = blockIdx.x >> 10, n = blockIdx.x & 1023, h = threadIdx.x;
  const float* zp = z + (long)(b*NN + n)*SEGN*HID;
  float a = 0;
#pragma unroll
  for (int g = 0; g < SEGN; ++g) a += zp[g*HID + h];
  enc[(long)(b*NN + n)*(2*HID) + s*HID + h] = a*0.25f;
}

// ---------------------------------------------------------------- final qkv proj (in_dim=128)
// q,k emitted bf16 (MFMA operands for k_fattn); v fp32.
template <int F>
__device__ __forceinline__ void fqkv_body(const float* __restrict__ enc,
    const void* __restrict__ wq, const void* __restrict__ wk,
    const void* __restrict__ wv,
    unsigned short* __restrict__ q, unsigned short* __restrict__ k,
    float* __restrict__ v, float* xs) {
  long r = blockIdx.x;
  int t = threadIdx.x;
  xs[t] = enc[r*128 + t];
  __syncthreads();
  if (t < 32) {
    long wr = (long)t*128; float a = 0;
    for (int e = 0; e < 128; ++e) a += xs[e]*ldw<F>(wq, wr + e);
    q[r*DKK + t] = f2b(a);
  } else if (t < 64) {
    long wr = (long)(t-32)*128; float a = 0;
    for (int e = 0; e < 128; ++e) a += xs[e]*ldw<F>(wk, wr + e);
    k[r*DKK + (t-32)] = f2b(a);
  } else {
    long wr = (long)(t-64)*128; float a = 0;
    for (int e = 0; e < 128; ++e) a += xs[e]*ldw<F>(wv, wr + e);
    v[r*HID + (t-64)] = a;
  }
}
__global__ __launch_bounds__(128) void k_fqkv(const float* __restrict__ enc,
    const void* wq, const void* wk, const void* wv,
    unsigned short* q, unsigned short* k, float* v, const int* __restrict__ flag) {
  __shared__ float xs[2*HID];
  if (*flag) fqkv_body<1>(enc, wq, wk, wv, q, k, v, xs);
  else       fqkv_body<0>(enc, wq, wk, wv, q, k, v, xs);
}

// ---------------------------------------------------------------- final attention (flash-MFMA) -> d_out
__global__ __launch_bounds__(256) void k_fattn(
    const unsigned short* __restrict__ qb, const unsigned short* __restrict__ kb,
    const float* __restrict__ vb, void* __restrict__ outp,
    const int* __restrict__ flag) {
  __shared__ unsigned short vt[64][72];
  __shared__ unsigned short pl[64][72];
  __shared__ float ob[64][66];
  int tid = threadIdx.x;
  int wv = tid >> 6, lane = tid & 63;
  int col = lane & 15, quad = lane >> 4;
  int b = blockIdx.x >> 4;
  int n0 = (blockIdx.x & 15) * 64;
  long gbase = (long)b * NN;

  s8v aq = *(const s8v*)(qb + (gbase + n0 + wv*16 + col)*DKK + quad*8);

  f4v acc[4];
#pragma unroll
  for (int t = 0; t < 4; ++t) acc[t] = (f4v){0.f,0.f,0.f,0.f};
  float mrow[4] = {-1e30f,-1e30f,-1e30f,-1e30f};
  float lrow[4] = {0.f,0.f,0.f,0.f};
  const float rs = 0.17677669529663687f;

  int kp = (tid & 31) * 2, dg = tid >> 5;

  for (int c0 = 0; c0 < NN; c0 += 64) {
    __syncthreads();
    {
      const float* vr0 = vb + (gbase + c0 + kp)*HID + dg*8;
      const float* vr1 = vr0 + HID;
      f4v u0 = *(const f4v*)vr0, u1 = *(const f4v*)(vr0 + 4);
      f4v w0 = *(const f4v*)vr1, w1 = *(const f4v*)(vr1 + 4);
#pragma unroll
      for (int i = 0; i < 4; ++i) {
        unsigned int p0 = (unsigned int)f2b(u0[i]) | ((unsigned int)f2b(w0[i]) << 16);
        unsigned int p1 = (unsigned int)f2b(u1[i]) | ((unsigned int)f2b(w1[i]) << 16);
        *(unsigned int*)&vt[dg*8 + i][kp] = p0;
        *(unsigned int*)&vt[dg*8 + 4 + i][kp] = p1;
      }
    }
    f4v s[4];
#pragma unroll
    for (int nt = 0; nt < 4; ++nt) {
      s8v bk = *(const s8v*)(kb + (gbase + c0 + nt*16 + col)*DKK + quad*8);
      s[nt] = __builtin_amdgcn_mfma_f32_16x16x32_bf16(aq, bk,
                (f4v){0.f,0.f,0.f,0.f}, 0, 0, 0);
    }
#pragma unroll
    for (int r = 0; r < 4; ++r) {
      float s0 = s[0][r]*rs, s1 = s[1][r]*rs, s2 = s[2][r]*rs, s3 = s[3][r]*rs;
      float mc = fmaxf(fmaxf(s0, s1), fmaxf(s2, s3));
#pragma unroll
      for (int off = 1; off < 16; off <<= 1) mc = fmaxf(mc, __shfl_xor(mc, off));
      float mn = fmaxf(mrow[r], mc);
      float al = expf(mrow[r] - mn);
      mrow[r] = mn;
      float p0 = expf(s0 - mn), p1 = expf(s1 - mn), p2 = expf(s2 - mn), p3 = expf(s3 - mn);
      float su = p0 + p1 + p2 + p3;
#pragma unroll
      for (int off = 1; off < 16; off <<= 1) su += __shfl_xor(su, off);
      lrow[r] = lrow[r]*al + su;
#pragma unroll
      for (int t = 0; t < 4; ++t) acc[t][r] *= al;
      int row = wv*16 + quad*4 + r;
      pl[row][col]      = f2b(p0);
      pl[row][16 + col] = f2b(p1);
      pl[row][32 + col] = f2b(p2);
      pl[row][48 + col] = f2b(p3);
    }
    __syncthreads();
#pragma unroll
    for (int ks = 0; ks < 2; ++ks) {
      s8v ap = *(const s8v*)&pl[wv*16 + col][ks*32 + quad*8];
#pragma unroll
      for (int nt = 0; nt < 4; ++nt) {
        s8v bv = *(const s8v*)&vt[nt*16 + col][ks*32 + quad*8];
        acc[nt] = __builtin_amdgcn_mfma_f32_16x16x32_bf16(ap, bv, acc[nt], 0, 0, 0);
      }
    }
  }

  float il[4];
#pragma unroll
  for (int r = 0; r < 4; ++r) il[r] = 1.f / lrow[r];
#pragma unroll
  for (int t = 0; t < 4; ++t) {
    int row = wv*16 + quad*4;
#pragma unroll
    for (int r = 0; r < 4; ++r)
      ob[row + r][t*16 + col] = acc[t][r] * il[r];
  }
  __syncthreads();
  int f = *flag;
#pragma unroll
  for (int rr = 0; rr < 16; ++rr) {
    int rl = wv*16 + rr;
    long idx = (gbase + n0 + rl)*HID + lane;
    float val = ob[rl][lane];
    if (f) ((float*)outp)[idx] = val;
    else   ((bf16*)outp)[idx] = __float2bfloat16(val);
  }
}

// ================================================================ launch
extern "C" void kernel_launch(void* const* d_in, const int* in_sizes, int n_in,
                              void* d_out, int out_size, void* d_ws, size_t ws_size,
                              hipStream_t stream) {
  static const int EXP[30] = {
    49152, 49152, 384, 128, 49152, 768, 16384, 256,
    524288, 8192, 524288, 256, 256, 256, 256, 256,
    8192, 8192, 16384, 524288, 8192, 524288, 256, 256,
    256, 256, 256, 4096, 4096, 8192
  };
  const size_t NEED = (size_t)(1048576 + 524288 + 524288 + 524288 + 1048576) * 4 + 64;
  bool ok = (n_in == 30) && (ws_size >= NEED) && (out_size == BB*NN*HID);
  if (ok) for (int i = 0; i < 30; ++i) ok = ok && (in_sizes[i] == EXP[i]);
  if (!ok) {
    k_zero<<<(BB*NN*HID + 255)/256, 256, 0, stream>>>((unsigned short*)d_out, BB*NN*HID);
    return;
  }

  float* z   = (float*)d_ws;             // [4,1024,4,64]
  float* enc = z   + 1048576;            // [4,1024,128]
  float* qb  = enc + 524288;             // bf16 q [*,1024,32]
  float* kb  = qb  + 524288;             // bf16 k
  float* vb  = kb  + 524288;             // fp32 v [*,1024,64]
  int*  flag = (int*)(vb + 1048576);

  k_detect<<<1, 256, 0, stream>>>(d_in[0], flag);

  const void *i_traffic=d_in[0], *i_user=d_in[1], *i_pw=d_in[2], *i_pb=d_in[3],
    *i_mw=d_in[4], *i_mb=d_in[5], *i_ow=d_in[6], *i_ob=d_in[7], *i_f1w=d_in[8],
    *i_f1b=d_in[9], *i_f2w=d_in[10], *i_f2b=d_in[11], *i_l1g=d_in[12],
    *i_l1b=d_in[13], *i_l2g=d_in[14], *i_l2b=d_in[15], *i_gwq=d_in[16],
    *i_gwk=d_in[17], *i_gwv=d_in[18], *i_gf1w=d_in[19], *i_gf1b=d_in[20],
    *i_gf2w=d_in[21], *i_gf2b=d_in[22], *i_gl1g=d_in[23], *i_gl1b=d_in[24],
    *i_gl2g=d_in[25], *i_gl2b=d_in[26], *i_cwq=d_in[27], *i_cwk=d_in[28],
    *i_cwv=d_in[29];

  const int FFG = BB*NN*SEGN/FRW;        // 256 blocks
  const int TAG = BB*NN*SEGN/TT;         // 256 blocks

  for (int s = 0; s < 2; ++s) {
    const void* x = s ? i_user : i_traffic;
    k_patch<<<BB*NN, 256, 0, stream>>>(x, i_pw, (long)s*HID*SEGL, i_pb, (long)s*HID, z, flag);
    for (int i = 0; i < 2; ++i) {
      long si = s*2 + i;
      k_tattn<<<TAG, 256, 0, stream>>>(z,
          i_mw, si*3*HID*HID, i_mb, si*3*HID, i_ow, si*HID*HID, i_ob, si*HID,
          i_l1g, si*HID, i_l1b, si*HID, flag);
      k_ffmfma<<<FFG, 256, 0, stream>>>(z,
          i_f1w, si*FFD*HID, i_f1b, si*FFD, i_f2w, si*HID*FFD, i_f2b, si*HID,
          i_l2g, si*HID, i_l2b, si*HID, flag);
      k_gqkv<<<16*NN, 128, 0, stream>>>(z,
          i_gwq, si*DKK*HID, i_gwk, si*DKK*HID, i_gwv, si*HID*HID,
          (unsigned short*)qb, (unsigned short*)kb, vb, flag);
      k_gattn<<<16*16, 256, 0, stream>>>(z,
          (const unsigned short*)qb, (const unsigned short*)kb, vb,
          i_gl1g, si*HID, i_gl1b, si*HID, flag);
      k_ffmfma<<<FFG, 256, 0, stream>>>(z,
          i_gf1w, si*FFD*HID, i_gf1b, si*FFD, i_gf2w, si*HID*FFD, i_gf2b, si*HID,
          i_gl2g, si*HID, i_gl2b, si*HID, flag);
    }
    k_pool<<<BB*NN, 64, 0, stream>>>(z, enc, s);
  }
  k_fqkv<<<BB*NN, 128, 0, stream>>>(enc, i_cwq, i_cwk, i_cwv,
      (unsigned short*)qb, (unsigned short*)kb, vb, flag);
  k_fattn<<<BB*16, 256, 0, stream>>>((const unsigned short*)qb,
      (const unsigned short*)kb, vb, d_out, flag);
}

// Round 10
// 1187.163 us; speedup vs baseline: 1.7170x; 1.0526x over previous
//
#include <hip/hip_runtime.h>
#include <hip/hip_bf16.h>
#include <math.h>

// Problem constants
#define BB 4
#define SEQL 12
#define NN 1024
#define SEGL 3
#define SEGN 4
#define HID 64
#define FFD 2048
#define DKK 32
#define NHH 8
#define HDD 8

using bf16 = __hip_bfloat16;
__device__ __forceinline__ float b2f(bf16 v) { return __bfloat162float(v); }

typedef __attribute__((ext_vector_type(8))) short s8v;   // 8 bf16 (4 VGPRs)
typedef __attribute__((ext_vector_type(4))) float f4v;   // MFMA C/D
typedef __attribute__((ext_vector_type(4))) unsigned short u4v;

__device__ __forceinline__ unsigned short f2b(float f) {
  bf16 h = __float2bfloat16(f);
  unsigned short u; __builtin_memcpy(&u, &h, 2); return u;
}
__device__ __forceinline__ float us2f(unsigned short u) {
  unsigned int e = ((unsigned int)u) << 16;
  float f; __builtin_memcpy(&f, &e, 4); return f;
}

// dtype-templated loads: F=1 fp32 storage, F=0 bf16 storage
template <int F>
__device__ __forceinline__ float ldw(const void* p, long i) {
  if (F) return ((const float*)p)[i];
  return b2f(((const bf16*)p)[i]);
}
template <int F>
__device__ __forceinline__ s8v ldfrag(const void* p, long elemOff) {
  if (F) {
    const float* fp = (const float*)p + elemOff;
    f4v u = *(const f4v*)fp, v = *(const f4v*)(fp + 4);
    s8v t;
    t[0]=f2b(u[0]); t[1]=f2b(u[1]); t[2]=f2b(u[2]); t[3]=f2b(u[3]);
    t[4]=f2b(v[0]); t[5]=f2b(v[1]); t[6]=f2b(v[2]); t[7]=f2b(v[3]);
    return t;
  }
  return *(const s8v*)((const unsigned short*)p + elemOff);
}
template <int F>
__device__ __forceinline__ f4v ldb4(const void* p, long i) {  // 4 consecutive vals
  if (F) return *(const f4v*)((const float*)p + i);
  u4v u = *(const u4v*)((const unsigned short*)p + i);
  f4v r; r[0]=us2f(u[0]); r[1]=us2f(u[1]); r[2]=us2f(u[2]); r[3]=us2f(u[3]);
  return r;
}

// ---------------------------------------------------------------- zero-fill d_out (guard path)
__global__ void k_zero(unsigned short* __restrict__ o, int n) {
  int i = blockIdx.x * 256 + threadIdx.x;
  if (i < n) o[i] = 0;
}

// ---------------------------------------------------------------- detect dtype
__global__ void k_detect(const void* __restrict__ x0, int* __restrict__ flag) {
  int t = threadIdx.x;
  int bad = 0;
  const bf16* p = (const bf16*)x0;
  for (int i = t; i < 512; i += 256) {
    float a = fabsf(b2f(p[i]));
    if (!(a < 1e4f) || (a != 0.f && a < 1e-4f)) bad = 1;
  }
  __shared__ int tot;
  if (t == 0) tot = 0;
  __syncthreads();
  unsigned long long m = __ballot(bad);
  if ((t & 63) == 0) atomicAdd(&tot, __popcll(m));
  __syncthreads();
  if (t == 0) *flag = (tot > 64) ? 1 : 0;   // 1 = fp32 storage, 0 = bf16
}

// ---------------------------------------------------------------- patch embed
template <int F>
__device__ __forceinline__ void patch_body(const void* __restrict__ x,
    const void* __restrict__ pw, long opw, const void* __restrict__ pb, long opb,
    float* __restrict__ z) {
  int b = blockIdx.x >> 10, n = blockIdx.x & 1023;
  int g = threadIdx.x >> 6, h = threadIdx.x & 63;
  float acc = ldw<F>(pb, opb + h);
#pragma unroll
  for (int l = 0; l < SEGL; ++l)
    acc += ldw<F>(x, (long)(b*SEQL + g*SEGL + l)*NN + n) * ldw<F>(pw, opw + h*SEGL + l);
  int i2 = h >> 1;
  float dv = expf((float)(2*i2) * (-logf(10000.f) / (float)HID));
  float ang = (float)g * dv;
  acc += (h & 1) ? cosf(ang) : sinf(ang);
  z[((long)(b*NN + n)*SEGN + g)*HID + h] = acc;
}
__global__ __launch_bounds__(256) void k_patch(const void* __restrict__ x,
    const void* __restrict__ pw, long opw, const void* __restrict__ pb, long opb,
    float* __restrict__ z, const int* __restrict__ flag) {
  if (*flag) patch_body<1>(x, pw, opw, pb, opb, z);
  else       patch_body<0>(x, pw, opw, pb, opb, z);
}

// ---------------------------------------------------------------- temporal MHA + LN1 (MFMA v2)
#define TT 64
template <int F>
__device__ __forceinline__ void tattn_body(float* __restrict__ z,
    const void* __restrict__ W, long oW, const void* __restrict__ bq, long obq,
    const void* __restrict__ WO, long oWO, const void* __restrict__ bo, long obo,
    const void* __restrict__ g1, long og1, const void* __restrict__ b1, long ob1,
    char* lds) {
  unsigned short (*qkvs)[200] = (unsigned short(*)[200])lds;        // 25600 B
  unsigned short (*ao)[72]    = (unsigned short(*)[72])(lds + 25600); // 9216 B
  float (*yb)[68]             = (float(*)[68])(lds + 34816);          // 17408 B
  int tid = threadIdx.x;
  int w = tid >> 6, lane = tid & 63;
  int col = lane & 15, quad = lane >> 4;
  long r0 = (long)blockIdx.x * TT;

  s8v bx[4][2];
#pragma unroll
  for (int mt = 0; mt < 4; ++mt) {
    const float* xr = z + (r0 + mt*16 + col) * HID;
#pragma unroll
    for (int ks = 0; ks < 2; ++ks) {
      const float* p = xr + ks*32 + quad*8;
      f4v u = *(const f4v*)p, v = *(const f4v*)(p + 4);
      s8v t;
      t[0]=f2b(u[0]); t[1]=f2b(u[1]); t[2]=f2b(u[2]); t[3]=f2b(u[3]);
      t[4]=f2b(v[0]); t[5]=f2b(v[1]); t[6]=f2b(v[2]); t[7]=f2b(v[3]);
      bx[mt][ks] = t;
    }
  }
#pragma unroll
  for (int nt = 0; nt < 3; ++nt) {
    int cbase = (w*3 + nt) * 16;
    s8v aw[2];
#pragma unroll
    for (int ks = 0; ks < 2; ++ks)
      aw[ks] = ldfrag<F>(W, oW + (long)(cbase + col)*HID + ks*32 + quad*8);
    f4v bv = ldb4<F>(bq, obq + cbase + quad*4);
#pragma unroll
    for (int mt = 0; mt < 4; ++mt) {
      f4v sv = (f4v){0.f,0.f,0.f,0.f};
#pragma unroll
      for (int ks = 0; ks < 2; ++ks)
        sv = __builtin_amdgcn_mfma_f32_16x16x32_bf16(aw[ks], bx[mt][ks], sv, 0, 0, 0);
      unsigned short pk[4];
#pragma unroll
      for (int r = 0; r < 4; ++r) pk[r] = f2b(sv[r] + bv[r]);
      *(unsigned long long*)&qkvs[mt*16 + col][cbase + quad*4] =
        (unsigned long long)pk[0] | ((unsigned long long)pk[1] << 16) |
        ((unsigned long long)pk[2] << 32) | ((unsigned long long)pk[3] << 48);
    }
  }
  __syncthreads();
  if (tid < 128) {
    int gi = tid >> 3, hd = tid & 7;
    int tl = gi * 4;
    float qv[4][8], kv[4][8], vv[4][8];
#pragma unroll
    for (int t4 = 0; t4 < 4; ++t4) {
      s8v qq = *(const s8v*)&qkvs[tl + t4][hd*8];
      s8v kk = *(const s8v*)&qkvs[tl + t4][64 + hd*8];
      s8v vq = *(const s8v*)&qkvs[tl + t4][128 + hd*8];
#pragma unroll
      for (int e = 0; e < 8; ++e) {
        qv[t4][e] = us2f((unsigned short)qq[e]);
        kv[t4][e] = us2f((unsigned short)kk[e]);
        vv[t4][e] = us2f((unsigned short)vq[e]);
      }
    }
    const float sc8 = 0.3535533905932738f;   // 1/sqrt(8)
#pragma unroll
    for (int qt = 0; qt < 4; ++qt) {
      float s[4]; float mx = -1e30f;
#pragma unroll
      for (int kt = 0; kt < 4; ++kt) {
        float d = 0;
#pragma unroll
        for (int e = 0; e < 8; ++e) d += qv[qt][e]*kv[kt][e];
        s[kt] = d*sc8; mx = fmaxf(mx, s[kt]);
      }
      float se = 0;
#pragma unroll
      for (int kt = 0; kt < 4; ++kt) { s[kt] = expf(s[kt]-mx); se += s[kt]; }
      float inv = 1.f/se;
      s8v outp;
#pragma unroll
      for (int e = 0; e < 8; ++e) {
        float o = 0;
#pragma unroll
        for (int kt = 0; kt < 4; ++kt) o += s[kt]*vv[kt][e];
        outp[e] = (short)f2b(o*inv);
      }
      *(s8v*)&ao[tl + qt][hd*8] = outp;
    }
  }
  __syncthreads();
  s8v awo[2];
#pragma unroll
  for (int ks = 0; ks < 2; ++ks)
    awo[ks] = ldfrag<F>(WO, oWO + (long)(w*16 + col)*HID + ks*32 + quad*8);
  f4v bov = ldb4<F>(bo, obo + w*16 + quad*4);
#pragma unroll
  for (int mt = 0; mt < 4; ++mt) {
    f4v ov = (f4v){0.f,0.f,0.f,0.f};
#pragma unroll
    for (int ks = 0; ks < 2; ++ks) {
      s8v bao = *(const s8v*)&ao[mt*16 + col][ks*32 + quad*8];
      ov = __builtin_amdgcn_mfma_f32_16x16x32_bf16(awo[ks], bao, ov, 0, 0, 0);
    }
    f4v yv;
#pragma unroll
    for (int r = 0; r < 4; ++r) yv[r] = ov[r] + bov[r];
    *(f4v*)&yb[mt*16 + col][w*16 + quad*4] = yv;
  }
  __syncthreads();
  float gg = ldw<F>(g1, og1 + lane), bb2 = ldw<F>(b1, ob1 + lane);
#pragma unroll
  for (int rr = 0; rr < 16; ++rr) {
    int row = w*16 + rr;
    long tok = r0 + row;
    float val = yb[row][lane] + z[tok*HID + lane];
    float s = val;
#pragma unroll
    for (int off = 32; off; off >>= 1) s += __shfl_xor(s, off);
    float m = s*(1.f/HID);
    float d = val - m, sq = d*d;
#pragma unroll
    for (int off = 32; off; off >>= 1) sq += __shfl_xor(sq, off);
    float rv = rsqrtf(sq*(1.f/HID) + 1e-5f);
    z[tok*HID + lane] = d*rv*gg + bb2;
  }
}
__global__ __launch_bounds__(256) void k_tattn(float* __restrict__ z,
    const void* W, long oW, const void* bqkv, long obq,
    const void* WO, long oWO, const void* bo, long obo,
    const void* g1, long og1, const void* b1, long ob1,
    const int* __restrict__ flag) {
  __shared__ __attribute__((aligned(16))) char lds[52224];
  if (*flag) tattn_body<1>(z, W, oW, bqkv, obq, WO, oWO, bo, obo, g1, og1, b1, ob1, lds);
  else       tattn_body<0>(z, W, oW, bqkv, obq, WO, oWO, bo, obo, g1, og1, b1, ob1, lds);
}

// ---------------------------------------------------------------- FF via MFMA bf16 (v5)
// v4 + __launch_bounds__(256,1): VGPR budget up to 512 (grid is 1 block/CU
// anyway), eliminating the v4 spills (VGPR_Count was 88 < 96 persistent regs).
// Both W1 and W2 fragments for a chunk prefetched up front: 16 independent
// 16B loads in flight -> one vmcnt drain -> 64 MFMA + LDS round-trip.
#define FRW 64
template <int F>
__device__ __forceinline__ void ffmfma_body(float* __restrict__ x,
    const void* __restrict__ W1, long o1, const void* __restrict__ B1, long ob1,
    const void* __restrict__ W2, long o2, const void* __restrict__ B2, long ob2,
    const void* __restrict__ G, long og, const void* __restrict__ Bt, long obt,
    char* ldsbuf) {
  int tid = threadIdx.x;
  int w = tid >> 6, lane = tid & 63;
  int col = lane & 15, quad = lane >> 4;
  long r0 = (long)blockIdx.x * FRW;
  unsigned short* hcw = (unsigned short*)(ldsbuf + w*9216);  // [64 xrow][72] shorts

  s8v bx[4][2];
#pragma unroll
  for (int rt = 0; rt < 4; ++rt) {
    const float* xr = x + (r0 + rt*16 + col) * HID;
#pragma unroll
    for (int ks = 0; ks < 2; ++ks) {
      const float* p = xr + ks*32 + quad*8;
      f4v u = *(const f4v*)p, v = *(const f4v*)(p + 4);
      s8v t;
      t[0]=f2b(u[0]); t[1]=f2b(u[1]); t[2]=f2b(u[2]); t[3]=f2b(u[3]);
      t[4]=f2b(v[0]); t[5]=f2b(v[1]); t[6]=f2b(v[2]); t[7]=f2b(v[3]);
      bx[rt][ks] = t;
    }
  }

  f4v acc[4][4];
#pragma unroll
  for (int m = 0; m < 4; ++m)
#pragma unroll
    for (int rt = 0; rt < 4; ++rt) acc[m][rt] = (f4v){0.f,0.f,0.f,0.f};

  const int hb0 = w * 512;
  for (int c = 0; c < 8; ++c) {
    const int hbase = hb0 + c*64;
    // ---- prefetch ALL weight fragments for this chunk (16 indep 16B loads)
    s8v aw1[4][2], aw2[2][4];
#pragma unroll
    for (int t = 0; t < 4; ++t)
#pragma unroll
      for (int ks = 0; ks < 2; ++ks)
        aw1[t][ks] = ldfrag<F>(W1, o1 + (long)(hbase + t*16 + col)*HID + ks*32 + quad*8);
#pragma unroll
    for (int ks2 = 0; ks2 < 2; ++ks2)
#pragma unroll
      for (int m = 0; m < 4; ++m)
        aw2[ks2][m] = ldfrag<F>(W2, o2 + (long)(m*16 + col)*FFD + hbase + ks2*32 + quad*8);
    // ---- GEMM1: S^T tiles -> relu -> hc (b64 packed writes)
#pragma unroll
    for (int t = 0; t < 4; ++t) {
      f4v bv = ldb4<F>(B1, ob1 + hbase + t*16 + quad*4);
#pragma unroll
      for (int rt = 0; rt < 4; ++rt) {
        f4v sv = (f4v){0.f,0.f,0.f,0.f};
#pragma unroll
        for (int ks = 0; ks < 2; ++ks)
          sv = __builtin_amdgcn_mfma_f32_16x16x32_bf16(aw1[t][ks], bx[rt][ks], sv, 0, 0, 0);
        unsigned short pk[4];
#pragma unroll
        for (int r = 0; r < 4; ++r) pk[r] = f2b(fmaxf(sv[r] + bv[r], 0.f));
        *(unsigned long long*)&hcw[(rt*16 + col)*72 + t*16 + quad*4] =
          (unsigned long long)pk[0] | ((unsigned long long)pk[1] << 16) |
          ((unsigned long long)pk[2] << 32) | ((unsigned long long)pk[3] << 48);
      }
    }
    // ---- GEMM2: acc += W2 @ Hc^T
#pragma unroll
    for (int ks2 = 0; ks2 < 2; ++ks2) {
      s8v bh[4];
#pragma unroll
      for (int rt = 0; rt < 4; ++rt)
        bh[rt] = *(const s8v*)&hcw[(rt*16 + col)*72 + ks2*32 + quad*8];
#pragma unroll
      for (int m = 0; m < 4; ++m)
#pragma unroll
        for (int rt = 0; rt < 4; ++rt)
          acc[m][rt] = __builtin_amdgcn_mfma_f32_16x16x32_bf16(aw2[ks2][m], bh[rt], acc[m][rt], 0, 0, 0);
    }
  }

  float* red0 = (float*)ldsbuf;               // [64][68]
  float* red1 = (float*)(ldsbuf + 17408);
  __syncthreads();
  if (w < 2) {
    float* rg = w ? red1 : red0;
#pragma unroll
    for (int m = 0; m < 4; ++m)
#pragma unroll
      for (int rt = 0; rt < 4; ++rt)
        *(f4v*)&rg[(rt*16 + col)*68 + m*16 + quad*4] = acc[m][rt];
  }
  __syncthreads();
  if (w >= 2) {
    float* rg = (w == 3) ? red1 : red0;
#pragma unroll
    for (int m = 0; m < 4; ++m)
#pragma unroll
      for (int rt = 0; rt < 4; ++rt) {
        float* pp = &rg[(rt*16 + col)*68 + m*16 + quad*4];
        f4v old = *(f4v*)pp;
        *(f4v*)pp = old + acc[m][rt];
      }
  }
  __syncthreads();
  float gg = ldw<F>(G, og + lane), bbt = ldw<F>(Bt, obt + lane);
  float b2v = ldw<F>(B2, ob2 + lane);
#pragma unroll
  for (int rr = 0; rr < 16; ++rr) {
    int rl = w*16 + rr;
    long grow = r0 + rl;
    float val = red0[rl*68 + lane] + red1[rl*68 + lane] + b2v + x[grow*HID + lane];
    float s = val;
#pragma unroll
    for (int off = 32; off; off >>= 1) s += __shfl_xor(s, off);
    float m = s * (1.f/HID);
    float d = val - m;
    float sq = d*d;
#pragma unroll
    for (int off = 32; off; off >>= 1) sq += __shfl_xor(sq, off);
    float rv = rsqrtf(sq*(1.f/HID) + 1e-5f);
    x[grow*HID + lane] = d*rv*gg + bbt;
  }
}
__global__ __launch_bounds__(256, 1) void k_ffmfma(float* __restrict__ x,
    const void* W1, long o1, const void* B1, long ob1,
    const void* W2, long o2, const void* B2, long ob2,
    const void* G, long og, const void* Bt, long obt,
    const int* __restrict__ flag) {
  __shared__ __attribute__((aligned(16))) char ldsbuf[4*9216];
  if (*flag) ffmfma_body<1>(x, W1, o1, B1, ob1, W2, o2, B2, ob2, G, og, Bt, obt, ldsbuf);
  else       ffmfma_body<0>(x, W1, o1, B1, ob1, W2, o2, B2, ob2, G, og, Bt, obt, ldsbuf);
}

// ---------------------------------------------------------------- graph qkv proj
template <int F>
__device__ __forceinline__ void gqkv_body(const float* __restrict__ z,
    const void* __restrict__ wq, long oq, const void* __restrict__ wk, long ok,
    const void* __restrict__ wv, long ov,
    unsigned short* __restrict__ q, unsigned short* __restrict__ k,
    float* __restrict__ v, float* xs) {
  int bg = blockIdx.x >> 10, n = blockIdx.x & 1023;
  int b = bg >> 2, g = bg & 3;
  const float* zp = z + ((long)(b*NN + n)*SEGN + g)*HID;
  int t = threadIdx.x;
  if (t < HID) xs[t] = zp[t];
  __syncthreads();
  long r = (long)bg*NN + n;
  if (t < 32) {
    long wr = oq + (long)t*HID; float a = 0;
    for (int e = 0; e < HID; ++e) a += xs[e]*ldw<F>(wq, wr + e);
    q[r*DKK + t] = f2b(a);
  } else if (t < 64) {
    long wr = ok + (long)(t-32)*HID; float a = 0;
    for (int e = 0; e < HID; ++e) a += xs[e]*ldw<F>(wk, wr + e);
    k[r*DKK + (t-32)] = f2b(a);
  } else {
    long wr = ov + (long)(t-64)*HID; float a = 0;
    for (int e = 0; e < HID; ++e) a += xs[e]*ldw<F>(wv, wr + e);
    v[r*HID + (t-64)] = a;
  }
}
__global__ __launch_bounds__(128) void k_gqkv(const float* __restrict__ z,
    const void* wq, long oq, const void* wk, long ok, const void* wv, long ov,
    unsigned short* q, unsigned short* k, float* v, const int* __restrict__ flag) {
  __shared__ float xs[HID];
  if (*flag) gqkv_body<1>(z, wq, oq, wk, ok, wv, ov, q, k, v, xs);
  else       gqkv_body<0>(z, wq, oq, wk, ok, wv, ov, q, k, v, xs);
}

// ---------------------------------------------------------------- graph attention (flash-MFMA)
__global__ __launch_bounds__(256) void k_gattn(float* __restrict__ z,
    const unsigned short* __restrict__ qb, const unsigned short* __restrict__ kb,
    const float* __restrict__ vb,
    const void* __restrict__ g1, long og1, const void* __restrict__ b1, long ob1,
    const int* __restrict__ flag) {
  int f = *flag;
  __shared__ unsigned short vt[64][72];   // [vdim][key]
  __shared__ unsigned short pl[64][72];   // [q_local][key]
  __shared__ float ob[64][66];
  int tid = threadIdx.x;
  int wv = tid >> 6, lane = tid & 63;
  int col = lane & 15, quad = lane >> 4;
  int bg = blockIdx.x >> 4;
  int n0 = (blockIdx.x & 15) * 64;
  long gbase = (long)bg * NN;

  s8v aq = *(const s8v*)(qb + (gbase + n0 + wv*16 + col)*DKK + quad*8);

  f4v acc[4];
#pragma unroll
  for (int t = 0; t < 4; ++t) acc[t] = (f4v){0.f,0.f,0.f,0.f};
  float mrow[4] = {-1e30f,-1e30f,-1e30f,-1e30f};
  float lrow[4] = {0.f,0.f,0.f,0.f};
  const float rs = 0.17677669529663687f;   // 1/sqrt(32)

  int kp = (tid & 31) * 2, dg = tid >> 5;

  for (int c0 = 0; c0 < NN; c0 += 64) {
    __syncthreads();
    {
      const float* vr0 = vb + (gbase + c0 + kp)*HID + dg*8;
      const float* vr1 = vr0 + HID;
      f4v u0 = *(const f4v*)vr0, u1 = *(const f4v*)(vr0 + 4);
      f4v w0 = *(const f4v*)vr1, w1 = *(const f4v*)(vr1 + 4);
#pragma unroll
      for (int i = 0; i < 4; ++i) {
        unsigned int p0 = (unsigned int)f2b(u0[i]) | ((unsigned int)f2b(w0[i]) << 16);
        unsigned int p1 = (unsigned int)f2b(u1[i]) | ((unsigned int)f2b(w1[i]) << 16);
        *(unsigned int*)&vt[dg*8 + i][kp] = p0;
        *(unsigned int*)&vt[dg*8 + 4 + i][kp] = p1;
      }
    }
    f4v s[4];
#pragma unroll
    for (int nt = 0; nt < 4; ++nt) {
      s8v bk = *(const s8v*)(kb + (gbase + c0 + nt*16 + col)*DKK + quad*8);
      s[nt] = __builtin_amdgcn_mfma_f32_16x16x32_bf16(aq, bk,
                (f4v){0.f,0.f,0.f,0.f}, 0, 0, 0);
    }
#pragma unroll
    for (int r = 0; r < 4; ++r) {
      float s0 = s[0][r]*rs, s1 = s[1][r]*rs, s2 = s[2][r]*rs, s3 = s[3][r]*rs;
      float mc = fmaxf(fmaxf(s0, s1), fmaxf(s2, s3));
#pragma unroll
      for (int off = 1; off < 16; off <<= 1) mc = fmaxf(mc, __shfl_xor(mc, off));
      float mn = fmaxf(mrow[r], mc);
      float al = expf(mrow[r] - mn);
      mrow[r] = mn;
      float p0 = expf(s0 - mn), p1 = expf(s1 - mn), p2 = expf(s2 - mn), p3 = expf(s3 - mn);
      float su = p0 + p1 + p2 + p3;
#pragma unroll
      for (int off = 1; off < 16; off <<= 1) su += __shfl_xor(su, off);
      lrow[r] = lrow[r]*al + su;
#pragma unroll
      for (int t = 0; t < 4; ++t) acc[t][r] *= al;
      int row = wv*16 + quad*4 + r;
      pl[row][col]      = f2b(p0);
      pl[row][16 + col] = f2b(p1);
      pl[row][32 + col] = f2b(p2);
      pl[row][48 + col] = f2b(p3);
    }
    __syncthreads();
#pragma unroll
    for (int ks = 0; ks < 2; ++ks) {
      s8v ap = *(const s8v*)&pl[wv*16 + col][ks*32 + quad*8];
#pragma unroll
      for (int nt = 0; nt < 4; ++nt) {
        s8v bv = *(const s8v*)&vt[nt*16 + col][ks*32 + quad*8];
        acc[nt] = __builtin_amdgcn_mfma_f32_16x16x32_bf16(ap, bv, acc[nt], 0, 0, 0);
      }
    }
  }

  float il[4];
#pragma unroll
  for (int r = 0; r < 4; ++r) il[r] = 1.f / lrow[r];
#pragma unroll
  for (int t = 0; t < 4; ++t) {
    int row = wv*16 + quad*4;
#pragma unroll
    for (int r = 0; r < 4; ++r)
      ob[row + r][t*16 + col] = acc[t][r] * il[r];
  }
  __syncthreads();
  int b = bg >> 2, g = bg & 3;
  float gg = f ? ((const float*)g1)[og1 + lane] : b2f(((const bf16*)g1)[og1 + lane]);
  float bb = f ? ((const float*)b1)[ob1 + lane] : b2f(((const bf16*)b1)[ob1 + lane]);
#pragma unroll
  for (int rr = 0; rr < 16; ++rr) {
    int rl = wv*16 + rr;
    int n = n0 + rl;
    float val = ob[rl][lane];
    float s = val;
#pragma unroll
    for (int off = 32; off; off >>= 1) s += __shfl_xor(s, off);
    float m = s*(1.f/HID);
    float d = val - m, sq = d*d;
#pragma unroll
    for (int off = 32; off; off >>= 1) sq += __shfl_xor(sq, off);
    float r = rsqrtf(sq*(1.f/HID) + 1e-5f);
    float* zp = z + ((long)(b*NN + n)*SEGN + g)*HID;
    zp[lane] = d*r*gg + bb + zp[lane];   // LN(att) + x
  }
}

// ---------------------------------------------------------------- pool over segments
__global__ __launch_bounds__(64) void k_pool(const float* __restrict__ z,
    float* __restrict__ enc, int s) {
  int b = blockIdx.x >> 10, n = blockIdx.x & 1023, h = threadIdx.x;
  const float* zp = z + (long)(b*NN + n)*SEGN*HID;
  float a = 0;
#pragma unroll
  for (int g = 0; g < SEGN; ++g) a += zp[g*HID + h];
  enc[(long)(b*NN + n)*(2*HID) + s*HID + h] = a*0.25f;
}

// ---------------------------------------------------------------- final qkv proj (in_dim=128)
template <int F>
__device__ __forceinline__ void fqkv_body(const float* __restrict__ enc,
    const void* __restrict__ wq, const void* __restrict__ wk,
    const void* __restrict__ wv,
    unsigned short* __restrict__ q, unsigned short* __restrict__ k,
    float* __restrict__ v, float* xs) {
  long r = blockIdx.x;
  int t = threadIdx.x;
  xs[t] = enc[r*128 + t];
  __syncthreads();
  if (t < 32) {
    long wr = (long)t*128; float a = 0;
    for (int e = 0; e < 128; ++e) a += xs[e]*ldw<F>(wq, wr + e);
    q[r*DKK + t] = f2b(a);
  } else if (t < 64) {
    long wr = (long)(t-32)*128; float a = 0;
    for (int e = 0; e < 128; ++e) a += xs[e]*ldw<F>(wk, wr + e);
    k[r*DKK + (t-32)] = f2b(a);
  } else {
    long wr = (long)(t-64)*128; float a = 0;
    for (int e = 0; e < 128; ++e) a += xs[e]*ldw<F>(wv, wr + e);
    v[r*HID + (t-64)] = a;
  }
}
__global__ __launch_bounds__(128) void k_fqkv(const float* __restrict__ enc,
    const void* wq, const void* wk, const void* wv,
    unsigned short* q, unsigned short* k, float* v, const int* __restrict__ flag) {
  __shared__ float xs[2*HID];
  if (*flag) fqkv_body<1>(enc, wq, wk, wv, q, k, v, xs);
  else       fqkv_body<0>(enc, wq, wk, wv, q, k, v, xs);
}

// ---------------------------------------------------------------- final attention (flash-MFMA) -> d_out
__global__ __launch_bounds__(256) void k_fattn(
    const unsigned short* __restrict__ qb, const unsigned short* __restrict__ kb,
    const float* __restrict__ vb, void* __restrict__ outp,
    const int* __restrict__ flag) {
  __shared__ unsigned short vt[64][72];
  __shared__ unsigned short pl[64][72];
  __shared__ float ob[64][66];
  int tid = threadIdx.x;
  int wv = tid >> 6, lane = tid & 63;
  int col = lane & 15, quad = lane >> 4;
  int b = blockIdx.x >> 4;
  int n0 = (blockIdx.x & 15) * 64;
  long gbase = (long)b * NN;

  s8v aq = *(const s8v*)(qb + (gbase + n0 + wv*16 + col)*DKK + quad*8);

  f4v acc[4];
#pragma unroll
  for (int t = 0; t < 4; ++t) acc[t] = (f4v){0.f,0.f,0.f,0.f};
  float mrow[4] = {-1e30f,-1e30f,-1e30f,-1e30f};
  float lrow[4] = {0.f,0.f,0.f,0.f};
  const float rs = 0.17677669529663687f;

  int kp = (tid & 31) * 2, dg = tid >> 5;

  for (int c0 = 0; c0 < NN; c0 += 64) {
    __syncthreads();
    {
      const float* vr0 = vb + (gbase + c0 + kp)*HID + dg*8;
      const float* vr1 = vr0 + HID;
      f4v u0 = *(const f4v*)vr0, u1 = *(const f4v*)(vr0 + 4);
      f4v w0 = *(const f4v*)vr1, w1 = *(const f4v*)(vr1 + 4);
#pragma unroll
      for (int i = 0; i < 4; ++i) {
        unsigned int p0 = (unsigned int)f2b(u0[i]) | ((unsigned int)f2b(w0[i]) << 16);
        unsigned int p1 = (unsigned int)f2b(u1[i]) | ((unsigned int)f2b(w1[i]) << 16);
        *(unsigned int*)&vt[dg*8 + i][kp] = p0;
        *(unsigned int*)&vt[dg*8 + 4 + i][kp] = p1;
      }
    }
    f4v s[4];
#pragma unroll
    for (int nt = 0; nt < 4; ++nt) {
      s8v bk = *(const s8v*)(kb + (gbase + c0 + nt*16 + col)*DKK + quad*8);
      s[nt] = __builtin_amdgcn_mfma_f32_16x16x32_bf16(aq, bk,
                (f4v){0.f,0.f,0.f,0.f}, 0, 0, 0);
    }
#pragma unroll
    for (int r = 0; r < 4; ++r) {
      float s0 = s[0][r]*rs, s1 = s[1][r]*rs, s2 = s[2][r]*rs, s3 = s[3][r]*rs;
      float mc = fmaxf(fmaxf(s0, s1), fmaxf(s2, s3));
#pragma unroll
      for (int off = 1; off < 16; off <<= 1) mc = fmaxf(mc, __shfl_xor(mc, off));
      float mn = fmaxf(mrow[r], mc);
      float al = expf(mrow[r] - mn);
      mrow[r] = mn;
      float p0 = expf(s0 - mn), p1 = expf(s1 - mn), p2 = expf(s2 - mn), p3 = expf(s3 - mn);
      float su = p0 + p1 + p2 + p3;
#pragma unroll
      for (int off = 1; off < 16; off <<= 1) su += __shfl_xor(su, off);
      lrow[r] = lrow[r]*al + su;
#pragma unroll
      for (int t = 0; t < 4; ++t) acc[t][r] *= al;
      int row = wv*16 + quad*4 + r;
      pl[row][col]      = f2b(p0);
      pl[row][16 + col] = f2b(p1);
      pl[row][32 + col] = f2b(p2);
      pl[row][48 + col] = f2b(p3);
    }
    __syncthreads();
#pragma unroll
    for (int ks = 0; ks < 2; ++ks) {
      s8v ap = *(const s8v*)&pl[wv*16 + col][ks*32 + quad*8];
#pragma unroll
      for (int nt = 0; nt < 4; ++nt) {
        s8v bv = *(const s8v*)&vt[nt*16 + col][ks*32 + quad*8];
        acc[nt] = __builtin_amdgcn_mfma_f32_16x16x32_bf16(ap, bv, acc[nt], 0, 0, 0);
      }
    }
  }

  float il[4];
#pragma unroll
  for (int r = 0; r < 4; ++r) il[r] = 1.f / lrow[r];
#pragma unroll
  for (int t = 0; t < 4; ++t) {
    int row = wv*16 + quad*4;
#pragma unroll
    for (int r = 0; r < 4; ++r)
      ob[row + r][t*16 + col] = acc[t][r] * il[r];
  }
  __syncthreads();
  int f = *flag;
#pragma unroll
  for (int rr = 0; rr < 16; ++rr) {
    int rl = wv*16 + rr;
    long idx = (gbase + n0 + rl)*HID + lane;
    float val = ob[rl][lane];
    if (f) ((float*)outp)[idx] = val;
    else   ((bf16*)outp)[idx] = __float2bfloat16(val);
  }
}

// ================================================================ launch
extern "C" void kernel_launch(void* const* d_in, const int* in_sizes, int n_in,
                              void* d_out, int out_size, void* d_ws, size_t ws_size,
                              hipStream_t stream) {
  static const int EXP[30] = {
    49152, 49152, 384, 128, 49152, 768, 16384, 256,
    524288, 8192, 524288, 256, 256, 256, 256, 256,
    8192, 8192, 16384, 524288, 8192, 524288, 256, 256,
    256, 256, 256, 4096, 4096, 8192
  };
  const size_t NEED = (size_t)(1048576 + 524288 + 524288 + 524288 + 1048576) * 4 + 64;
  bool ok = (n_in == 30) && (ws_size >= NEED) && (out_size == BB*NN*HID);
  if (ok) for (int i = 0; i < 30; ++i) ok = ok && (in_sizes[i] == EXP[i]);
  if (!ok) {
    k_zero<<<(BB*NN*HID + 255)/256, 256, 0, stream>>>((unsigned short*)d_out, BB*NN*HID);
    return;
  }

  float* z   = (float*)d_ws;             // [4,1024,4,64]
  float* enc = z   + 1048576;            // [4,1024,128]
  float* qb  = enc + 524288;             // bf16 q [*,1024,32]
  float* kb  = qb  + 524288;             // bf16 k
  float* vb  = kb  + 524288;             // fp32 v [*,1024,64]
  int*  flag = (int*)(vb + 1048576);

  k_detect<<<1, 256, 0, stream>>>(d_in[0], flag);

  const void *i_traffic=d_in[0], *i_user=d_in[1], *i_pw=d_in[2], *i_pb=d_in[3],
    *i_mw=d_in[4], *i_mb=d_in[5], *i_ow=d_in[6], *i_ob=d_in[7], *i_f1w=d_in[8],
    *i_f1b=d_in[9], *i_f2w=d_in[10], *i_f2b=d_in[11], *i_l1g=d_in[12],
    *i_l1b=d_in[13], *i_l2g=d_in[14], *i_l2b=d_in[15], *i_gwq=d_in[16],
    *i_gwk=d_in[17], *i_gwv=d_in[18], *i_gf1w=d_in[19], *i_gf1b=d_in[20],
    *i_gf2w=d_in[21], *i_gf2b=d_in[22], *i_gl1g=d_in[23], *i_gl1b=d_in[24],
    *i_gl2g=d_in[25], *i_gl2b=d_in[26], *i_cwq=d_in[27], *i_cwk=d_in[28],
    *i_cwv=d_in[29];

  const int FFG = BB*NN*SEGN/FRW;        // 256 blocks
  const int TAG = BB*NN*SEGN/TT;         // 256 blocks

  for (int s = 0; s < 2; ++s) {
    const void* x = s ? i_user : i_traffic;
    k_patch<<<BB*NN, 256, 0, stream>>>(x, i_pw, (long)s*HID*SEGL, i_pb, (long)s*HID, z, flag);
    for (int i = 0; i < 2; ++i) {
      long si = s*2 + i;
      k_tattn<<<TAG, 256, 0, stream>>>(z,
          i_mw, si*3*HID*HID, i_mb, si*3*HID, i_ow, si*HID*HID, i_ob, si*HID,
          i_l1g, si*HID, i_l1b, si*HID, flag);
      k_ffmfma<<<FFG, 256, 0, stream>>>(z,
          i_f1w, si*FFD*HID, i_f1b, si*FFD, i_f2w, si*HID*FFD, i_f2b, si*HID,
          i_l2g, si*HID, i_l2b, si*HID, flag);
      k_gqkv<<<16*NN, 128, 0, stream>>>(z,
          i_gwq, si*DKK*HID, i_gwk, si*DKK*HID, i_gwv, si*HID*HID,
          (unsigned short*)qb, (unsigned short*)kb, vb, flag);
      k_gattn<<<16*16, 256, 0, stream>>>(z,
          (const unsigned short*)qb, (const unsigned short*)kb, vb,
          i_gl1g, si*HID, i_gl1b, si*HID, flag);
      k_ffmfma<<<FFG, 256, 0, stream>>>(z,
          i_gf1w, si*FFD*HID, i_gf1b, si*FFD, i_gf2w, si*HID*FFD, i_gf2b, si*HID,
          i_gl2g, si*HID, i_gl2b, si*HID, flag);
    }
    k_pool<<<BB*NN, 64, 0, stream>>>(z, enc, s);
  }
  k_fqkv<<<BB*NN, 128, 0, stream>>>(enc, i_cwq, i_cwk, i_cwv,
      (unsigned short*)qb, (unsigned short*)kb, vb, flag);
  k_fattn<<<BB*16, 256, 0, stream>>>((const unsigned short*)qb,
      (const unsigned short*)kb, vb, d_out, flag);
}

// Round 11
// 959.656 us; speedup vs baseline: 2.1240x; 1.2371x over previous
//
#include <hip/hip_runtime.h>
#include <hip/hip_bf16.h>
#include <math.h>

// Problem constants
#define BB 4
#define SEQL 12
#define NN 1024
#define SEGL 3
#define SEGN 4
#define HID 64
#define FFD 2048
#define DKK 32
#define NHH 8
#define HDD 8

using bf16 = __hip_bfloat16;
__device__ __forceinline__ float b2f(bf16 v) { return __bfloat162float(v); }

typedef __attribute__((ext_vector_type(8))) short s8v;   // 8 bf16 (4 VGPRs)
typedef __attribute__((ext_vector_type(4))) float f4v;   // MFMA C/D
typedef __attribute__((ext_vector_type(4))) unsigned short u4v;

__device__ __forceinline__ unsigned short f2b(float f) {
  bf16 h = __float2bfloat16(f);
  unsigned short u; __builtin_memcpy(&u, &h, 2); return u;
}
__device__ __forceinline__ float us2f(unsigned short u) {
  unsigned int e = ((unsigned int)u) << 16;
  float f; __builtin_memcpy(&f, &e, 4); return f;
}

// dtype-templated loads: F=1 fp32 storage, F=0 bf16 storage
template <int F>
__device__ __forceinline__ float ldw(const void* p, long i) {
  if (F) return ((const float*)p)[i];
  return b2f(((const bf16*)p)[i]);
}
template <int F>
__device__ __forceinline__ s8v ldfrag(const void* p, long elemOff) {
  if (F) {
    const float* fp = (const float*)p + elemOff;
    f4v u = *(const f4v*)fp, v = *(const f4v*)(fp + 4);
    s8v t;
    t[0]=f2b(u[0]); t[1]=f2b(u[1]); t[2]=f2b(u[2]); t[3]=f2b(u[3]);
    t[4]=f2b(v[0]); t[5]=f2b(v[1]); t[6]=f2b(v[2]); t[7]=f2b(v[3]);
    return t;
  }
  return *(const s8v*)((const unsigned short*)p + elemOff);
}
template <int F>
__device__ __forceinline__ f4v ldb4(const void* p, long i) {  // 4 consecutive vals
  if (F) return *(const f4v*)((const float*)p + i);
  u4v u = *(const u4v*)((const unsigned short*)p + i);
  f4v r; r[0]=us2f(u[0]); r[1]=us2f(u[1]); r[2]=us2f(u[2]); r[3]=us2f(u[3]);
  return r;
}

// ---------------------------------------------------------------- zero-fill d_out (guard path)
__global__ void k_zero(unsigned short* __restrict__ o, int n) {
  int i = blockIdx.x * 256 + threadIdx.x;
  if (i < n) o[i] = 0;
}

// ---------------------------------------------------------------- detect dtype
__global__ void k_detect(const void* __restrict__ x0, int* __restrict__ flag) {
  int t = threadIdx.x;
  int bad = 0;
  const bf16* p = (const bf16*)x0;
  for (int i = t; i < 512; i += 256) {
    float a = fabsf(b2f(p[i]));
    if (!(a < 1e4f) || (a != 0.f && a < 1e-4f)) bad = 1;
  }
  __shared__ int tot;
  if (t == 0) tot = 0;
  __syncthreads();
  unsigned long long m = __ballot(bad);
  if ((t & 63) == 0) atomicAdd(&tot, __popcll(m));
  __syncthreads();
  if (t == 0) *flag = (tot > 64) ? 1 : 0;   // 1 = fp32 storage, 0 = bf16
}

// ---------------------------------------------------------------- patch embed
template <int F>
__device__ __forceinline__ void patch_body(const void* __restrict__ x,
    const void* __restrict__ pw, long opw, const void* __restrict__ pb, long opb,
    float* __restrict__ z) {
  int b = blockIdx.x >> 10, n = blockIdx.x & 1023;
  int g = threadIdx.x >> 6, h = threadIdx.x & 63;
  float acc = ldw<F>(pb, opb + h);
#pragma unroll
  for (int l = 0; l < SEGL; ++l)
    acc += ldw<F>(x, (long)(b*SEQL + g*SEGL + l)*NN + n) * ldw<F>(pw, opw + h*SEGL + l);
  int i2 = h >> 1;
  float dv = expf((float)(2*i2) * (-logf(10000.f) / (float)HID));
  float ang = (float)g * dv;
  acc += (h & 1) ? cosf(ang) : sinf(ang);
  z[((long)(b*NN + n)*SEGN + g)*HID + h] = acc;
}
__global__ __launch_bounds__(256) void k_patch(const void* __restrict__ x,
    const void* __restrict__ pw, long opw, const void* __restrict__ pb, long opb,
    float* __restrict__ z, const int* __restrict__ flag) {
  if (*flag) patch_body<1>(x, pw, opw, pb, opb, z);
  else       patch_body<0>(x, pw, opw, pb, opb, z);
}

// ---------------------------------------------------------------- temporal MHA + LN1 (MFMA v2)
#define TT 64
template <int F>
__device__ __forceinline__ void tattn_body(float* __restrict__ z,
    const void* __restrict__ W, long oW, const void* __restrict__ bq, long obq,
    const void* __restrict__ WO, long oWO, const void* __restrict__ bo, long obo,
    const void* __restrict__ g1, long og1, const void* __restrict__ b1, long ob1,
    char* lds) {
  unsigned short (*qkvs)[200] = (unsigned short(*)[200])lds;        // 25600 B
  unsigned short (*ao)[72]    = (unsigned short(*)[72])(lds + 25600); // 9216 B
  float (*yb)[68]             = (float(*)[68])(lds + 34816);          // 17408 B
  int tid = threadIdx.x;
  int w = tid >> 6, lane = tid & 63;
  int col = lane & 15, quad = lane >> 4;
  long r0 = (long)blockIdx.x * TT;

  s8v bx[4][2];
#pragma unroll
  for (int mt = 0; mt < 4; ++mt) {
    const float* xr = z + (r0 + mt*16 + col) * HID;
#pragma unroll
    for (int ks = 0; ks < 2; ++ks) {
      const float* p = xr + ks*32 + quad*8;
      f4v u = *(const f4v*)p, v = *(const f4v*)(p + 4);
      s8v t;
      t[0]=f2b(u[0]); t[1]=f2b(u[1]); t[2]=f2b(u[2]); t[3]=f2b(u[3]);
      t[4]=f2b(v[0]); t[5]=f2b(v[1]); t[6]=f2b(v[2]); t[7]=f2b(v[3]);
      bx[mt][ks] = t;
    }
  }
#pragma unroll
  for (int nt = 0; nt < 3; ++nt) {
    int cbase = (w*3 + nt) * 16;
    s8v aw[2];
#pragma unroll
    for (int ks = 0; ks < 2; ++ks)
      aw[ks] = ldfrag<F>(W, oW + (long)(cbase + col)*HID + ks*32 + quad*8);
    f4v bv = ldb4<F>(bq, obq + cbase + quad*4);
#pragma unroll
    for (int mt = 0; mt < 4; ++mt) {
      f4v sv = (f4v){0.f,0.f,0.f,0.f};
#pragma unroll
      for (int ks = 0; ks < 2; ++ks)
        sv = __builtin_amdgcn_mfma_f32_16x16x32_bf16(aw[ks], bx[mt][ks], sv, 0, 0, 0);
      unsigned short pk[4];
#pragma unroll
      for (int r = 0; r < 4; ++r) pk[r] = f2b(sv[r] + bv[r]);
      *(unsigned long long*)&qkvs[mt*16 + col][cbase + quad*4] =
        (unsigned long long)pk[0] | ((unsigned long long)pk[1] << 16) |
        ((unsigned long long)pk[2] << 32) | ((unsigned long long)pk[3] << 48);
    }
  }
  __syncthreads();
  if (tid < 128) {
    int gi = tid >> 3, hd = tid & 7;
    int tl = gi * 4;
    float qv[4][8], kv[4][8], vv[4][8];
#pragma unroll
    for (int t4 = 0; t4 < 4; ++t4) {
      s8v qq = *(const s8v*)&qkvs[tl + t4][hd*8];
      s8v kk = *(const s8v*)&qkvs[tl + t4][64 + hd*8];
      s8v vq = *(const s8v*)&qkvs[tl + t4][128 + hd*8];
#pragma unroll
      for (int e = 0; e < 8; ++e) {
        qv[t4][e] = us2f((unsigned short)qq[e]);
        kv[t4][e] = us2f((unsigned short)kk[e]);
        vv[t4][e] = us2f((unsigned short)vq[e]);
      }
    }
    const float sc8 = 0.3535533905932738f;   // 1/sqrt(8)
#pragma unroll
    for (int qt = 0; qt < 4; ++qt) {
      float s[4]; float mx = -1e30f;
#pragma unroll
      for (int kt = 0; kt < 4; ++kt) {
        float d = 0;
#pragma unroll
        for (int e = 0; e < 8; ++e) d += qv[qt][e]*kv[kt][e];
        s[kt] = d*sc8; mx = fmaxf(mx, s[kt]);
      }
      float se = 0;
#pragma unroll
      for (int kt = 0; kt < 4; ++kt) { s[kt] = expf(s[kt]-mx); se += s[kt]; }
      float inv = 1.f/se;
      s8v outp;
#pragma unroll
      for (int e = 0; e < 8; ++e) {
        float o = 0;
#pragma unroll
        for (int kt = 0; kt < 4; ++kt) o += s[kt]*vv[kt][e];
        outp[e] = (short)f2b(o*inv);
      }
      *(s8v*)&ao[tl + qt][hd*8] = outp;
    }
  }
  __syncthreads();
  s8v awo[2];
#pragma unroll
  for (int ks = 0; ks < 2; ++ks)
    awo[ks] = ldfrag<F>(WO, oWO + (long)(w*16 + col)*HID + ks*32 + quad*8);
  f4v bov = ldb4<F>(bo, obo + w*16 + quad*4);
#pragma unroll
  for (int mt = 0; mt < 4; ++mt) {
    f4v ov = (f4v){0.f,0.f,0.f,0.f};
#pragma unroll
    for (int ks = 0; ks < 2; ++ks) {
      s8v bao = *(const s8v*)&ao[mt*16 + col][ks*32 + quad*8];
      ov = __builtin_amdgcn_mfma_f32_16x16x32_bf16(awo[ks], bao, ov, 0, 0, 0);
    }
    f4v yv;
#pragma unroll
    for (int r = 0; r < 4; ++r) yv[r] = ov[r] + bov[r];
    *(f4v*)&yb[mt*16 + col][w*16 + quad*4] = yv;
  }
  __syncthreads();
  float gg = ldw<F>(g1, og1 + lane), bb2 = ldw<F>(b1, ob1 + lane);
#pragma unroll
  for (int rr = 0; rr < 16; ++rr) {
    int row = w*16 + rr;
    long tok = r0 + row;
    float val = yb[row][lane] + z[tok*HID + lane];
    float s = val;
#pragma unroll
    for (int off = 32; off; off >>= 1) s += __shfl_xor(s, off);
    float m = s*(1.f/HID);
    float d = val - m, sq = d*d;
#pragma unroll
    for (int off = 32; off; off >>= 1) sq += __shfl_xor(sq, off);
    float rv = rsqrtf(sq*(1.f/HID) + 1e-5f);
    z[tok*HID + lane] = d*rv*gg + bb2;
  }
}
__global__ __launch_bounds__(256) void k_tattn(float* __restrict__ z,
    const void* W, long oW, const void* bqkv, long obq,
    const void* WO, long oWO, const void* bo, long obo,
    const void* g1, long og1, const void* b1, long ob1,
    const int* __restrict__ flag) {
  __shared__ __attribute__((aligned(16))) char lds[52224];
  if (*flag) tattn_body<1>(z, W, oW, bqkv, obq, WO, oWO, bo, obo, g1, og1, b1, ob1, lds);
  else       tattn_body<0>(z, W, oW, bqkv, obq, WO, oWO, bo, obo, g1, og1, b1, ob1, lds);
}

// ---------------------------------------------------------------- FF via MFMA bf16 (v5)
#define FRW 64
template <int F>
__device__ __forceinline__ void ffmfma_body(float* __restrict__ x,
    const void* __restrict__ W1, long o1, const void* __restrict__ B1, long ob1,
    const void* __restrict__ W2, long o2, const void* __restrict__ B2, long ob2,
    const void* __restrict__ G, long og, const void* __restrict__ Bt, long obt,
    char* ldsbuf) {
  int tid = threadIdx.x;
  int w = tid >> 6, lane = tid & 63;
  int col = lane & 15, quad = lane >> 4;
  long r0 = (long)blockIdx.x * FRW;
  unsigned short* hcw = (unsigned short*)(ldsbuf + w*9216);  // [64 xrow][72] shorts

  s8v bx[4][2];
#pragma unroll
  for (int rt = 0; rt < 4; ++rt) {
    const float* xr = x + (r0 + rt*16 + col) * HID;
#pragma unroll
    for (int ks = 0; ks < 2; ++ks) {
      const float* p = xr + ks*32 + quad*8;
      f4v u = *(const f4v*)p, v = *(const f4v*)(p + 4);
      s8v t;
      t[0]=f2b(u[0]); t[1]=f2b(u[1]); t[2]=f2b(u[2]); t[3]=f2b(u[3]);
      t[4]=f2b(v[0]); t[5]=f2b(v[1]); t[6]=f2b(v[2]); t[7]=f2b(v[3]);
      bx[rt][ks] = t;
    }
  }

  f4v acc[4][4];
#pragma unroll
  for (int m = 0; m < 4; ++m)
#pragma unroll
    for (int rt = 0; rt < 4; ++rt) acc[m][rt] = (f4v){0.f,0.f,0.f,0.f};

  const int hb0 = w * 512;
  for (int c = 0; c < 8; ++c) {
    const int hbase = hb0 + c*64;
    s8v aw1[4][2], aw2[2][4];
#pragma unroll
    for (int t = 0; t < 4; ++t)
#pragma unroll
      for (int ks = 0; ks < 2; ++ks)
        aw1[t][ks] = ldfrag<F>(W1, o1 + (long)(hbase + t*16 + col)*HID + ks*32 + quad*8);
#pragma unroll
    for (int ks2 = 0; ks2 < 2; ++ks2)
#pragma unroll
      for (int m = 0; m < 4; ++m)
        aw2[ks2][m] = ldfrag<F>(W2, o2 + (long)(m*16 + col)*FFD + hbase + ks2*32 + quad*8);
#pragma unroll
    for (int t = 0; t < 4; ++t) {
      f4v bv = ldb4<F>(B1, ob1 + hbase + t*16 + quad*4);
#pragma unroll
      for (int rt = 0; rt < 4; ++rt) {
        f4v sv = (f4v){0.f,0.f,0.f,0.f};
#pragma unroll
        for (int ks = 0; ks < 2; ++ks)
          sv = __builtin_amdgcn_mfma_f32_16x16x32_bf16(aw1[t][ks], bx[rt][ks], sv, 0, 0, 0);
        unsigned short pk[4];
#pragma unroll
        for (int r = 0; r < 4; ++r) pk[r] = f2b(fmaxf(sv[r] + bv[r], 0.f));
        *(unsigned long long*)&hcw[(rt*16 + col)*72 + t*16 + quad*4] =
          (unsigned long long)pk[0] | ((unsigned long long)pk[1] << 16) |
          ((unsigned long long)pk[2] << 32) | ((unsigned long long)pk[3] << 48);
      }
    }
#pragma unroll
    for (int ks2 = 0; ks2 < 2; ++ks2) {
      s8v bh[4];
#pragma unroll
      for (int rt = 0; rt < 4; ++rt)
        bh[rt] = *(const s8v*)&hcw[(rt*16 + col)*72 + ks2*32 + quad*8];
#pragma unroll
      for (int m = 0; m < 4; ++m)
#pragma unroll
        for (int rt = 0; rt < 4; ++rt)
          acc[m][rt] = __builtin_amdgcn_mfma_f32_16x16x32_bf16(aw2[ks2][m], bh[rt], acc[m][rt], 0, 0, 0);
    }
  }

  float* red0 = (float*)ldsbuf;               // [64][68]
  float* red1 = (float*)(ldsbuf + 17408);
  __syncthreads();
  if (w < 2) {
    float* rg = w ? red1 : red0;
#pragma unroll
    for (int m = 0; m < 4; ++m)
#pragma unroll
      for (int rt = 0; rt < 4; ++rt)
        *(f4v*)&rg[(rt*16 + col)*68 + m*16 + quad*4] = acc[m][rt];
  }
  __syncthreads();
  if (w >= 2) {
    float* rg = (w == 3) ? red1 : red0;
#pragma unroll
    for (int m = 0; m < 4; ++m)
#pragma unroll
      for (int rt = 0; rt < 4; ++rt) {
        float* pp = &rg[(rt*16 + col)*68 + m*16 + quad*4];
        f4v old = *(f4v*)pp;
        *(f4v*)pp = old + acc[m][rt];
      }
  }
  __syncthreads();
  float gg = ldw<F>(G, og + lane), bbt = ldw<F>(Bt, obt + lane);
  float b2v = ldw<F>(B2, ob2 + lane);
#pragma unroll
  for (int rr = 0; rr < 16; ++rr) {
    int rl = w*16 + rr;
    long grow = r0 + rl;
    float val = red0[rl*68 + lane] + red1[rl*68 + lane] + b2v + x[grow*HID + lane];
    float s = val;
#pragma unroll
    for (int off = 32; off; off >>= 1) s += __shfl_xor(s, off);
    float m = s * (1.f/HID);
    float d = val - m;
    float sq = d*d;
#pragma unroll
    for (int off = 32; off; off >>= 1) sq += __shfl_xor(sq, off);
    float rv = rsqrtf(sq*(1.f/HID) + 1e-5f);
    x[grow*HID + lane] = d*rv*gg + bbt;
  }
}
__global__ __launch_bounds__(256, 1) void k_ffmfma(float* __restrict__ x,
    const void* W1, long o1, const void* B1, long ob1,
    const void* W2, long o2, const void* B2, long ob2,
    const void* G, long og, const void* Bt, long obt,
    const int* __restrict__ flag) {
  __shared__ __attribute__((aligned(16))) char ldsbuf[4*9216];
  if (*flag) ffmfma_body<1>(x, W1, o1, B1, ob1, W2, o2, B2, ob2, G, og, Bt, obt, ldsbuf);
  else       ffmfma_body<0>(x, W1, o1, B1, ob1, W2, o2, B2, ob2, G, og, Bt, obt, ldsbuf);
}

// ---------------------------------------------------------------- graph qkv proj (MFMA v2)
// 64 rows (one bg, 64 nodes)/block, 256 blocks, 256 threads.
// B = z rows (bf16 frags); wave w owns output-col tiles 2w,2w+1
// (q: tiles 0-1, k: 2-3, v: 4-7). C-layout packs: b64 bf16 stores (q,k),
// f4v stores (v). Zero barriers, zero LDS.
template <int F>
__device__ __forceinline__ void gqkv_body(const float* __restrict__ z,
    const void* __restrict__ wq, long oq, const void* __restrict__ wk, long ok,
    const void* __restrict__ wv, long ov,
    unsigned short* __restrict__ q, unsigned short* __restrict__ k,
    float* __restrict__ v) {
  int tid = threadIdx.x;
  int w = tid >> 6, lane = tid & 63;
  int col = lane & 15, quad = lane >> 4;
  int bg = blockIdx.x >> 4;
  int n0 = (blockIdx.x & 15) * 64;
  int b = bg >> 2, g = bg & 3;
  long gbase = (long)bg * NN;

  // B-fragments from z rows n0+rt*16+col
  s8v bx[4][2];
#pragma unroll
  for (int rt = 0; rt < 4; ++rt) {
    const float* xr = z + ((long)(b*NN + n0 + rt*16 + col)*SEGN + g)*HID;
#pragma unroll
    for (int ks = 0; ks < 2; ++ks) {
      const float* p = xr + ks*32 + quad*8;
      f4v u = *(const f4v*)p, vv = *(const f4v*)(p + 4);
      s8v t;
      t[0]=f2b(u[0]); t[1]=f2b(u[1]); t[2]=f2b(u[2]); t[3]=f2b(u[3]);
      t[4]=f2b(vv[0]); t[5]=f2b(vv[1]); t[6]=f2b(vv[2]); t[7]=f2b(vv[3]);
      bx[rt][ks] = t;
    }
  }

#pragma unroll
  for (int tt = 0; tt < 2; ++tt) {
    int ct = w*2 + tt;                        // wave-uniform
    const void* wp; long wo; int co; int kind; // 0=q,1=k,2=v
    if (ct < 2)      { wp = wq; wo = oq; co = ct*16;      kind = 0; }
    else if (ct < 4) { wp = wk; wo = ok; co = (ct-2)*16;  kind = 1; }
    else             { wp = wv; wo = ov; co = (ct-4)*16;  kind = 2; }
    s8v aw[2];
#pragma unroll
    for (int ks = 0; ks < 2; ++ks)
      aw[ks] = ldfrag<F>(wp, wo + (long)(co + col)*HID + ks*32 + quad*8);
#pragma unroll
    for (int rt = 0; rt < 4; ++rt) {
      f4v sv = (f4v){0.f,0.f,0.f,0.f};
#pragma unroll
      for (int ks = 0; ks < 2; ++ks)
        sv = __builtin_amdgcn_mfma_f32_16x16x32_bf16(aw[ks], bx[rt][ks], sv, 0, 0, 0);
      long row = gbase + n0 + rt*16 + col;
      if (kind == 2) {
        *(f4v*)&v[row*HID + co + quad*4] = sv;
      } else {
        unsigned short pk[4];
#pragma unroll
        for (int r = 0; r < 4; ++r) pk[r] = f2b(sv[r]);
        unsigned short* dst = kind ? k : q;
        *(unsigned long long*)&dst[row*DKK + co + quad*4] =
          (unsigned long long)pk[0] | ((unsigned long long)pk[1] << 16) |
          ((unsigned long long)pk[2] << 32) | ((unsigned long long)pk[3] << 48);
      }
    }
  }
}
__global__ __launch_bounds__(256) void k_gqkv(const float* __restrict__ z,
    const void* wq, long oq, const void* wk, long ok, const void* wv, long ov,
    unsigned short* q, unsigned short* k, float* v, const int* __restrict__ flag) {
  if (*flag) gqkv_body<1>(z, wq, oq, wk, ok, wv, ov, q, k, v);
  else       gqkv_body<0>(z, wq, oq, wk, ok, wv, ov, q, k, v);
}

// ---------------------------------------------------------------- graph attention (flash-MFMA)
__global__ __launch_bounds__(256) void k_gattn(float* __restrict__ z,
    const unsigned short* __restrict__ qb, const unsigned short* __restrict__ kb,
    const float* __restrict__ vb,
    const void* __restrict__ g1, long og1, const void* __restrict__ b1, long ob1,
    const int* __restrict__ flag) {
  int f = *flag;
  __shared__ unsigned short vt[64][72];   // [vdim][key]
  __shared__ unsigned short pl[64][72];   // [q_local][key]
  __shared__ float ob[64][66];
  int tid = threadIdx.x;
  int wv = tid >> 6, lane = tid & 63;
  int col = lane & 15, quad = lane >> 4;
  int bg = blockIdx.x >> 4;
  int n0 = (blockIdx.x & 15) * 64;
  long gbase = (long)bg * NN;

  s8v aq = *(const s8v*)(qb + (gbase + n0 + wv*16 + col)*DKK + quad*8);

  f4v acc[4];
#pragma unroll
  for (int t = 0; t < 4; ++t) acc[t] = (f4v){0.f,0.f,0.f,0.f};
  float mrow[4] = {-1e30f,-1e30f,-1e30f,-1e30f};
  float lrow[4] = {0.f,0.f,0.f,0.f};
  const float rs = 0.17677669529663687f;   // 1/sqrt(32)

  int kp = (tid & 31) * 2, dg = tid >> 5;

  for (int c0 = 0; c0 < NN; c0 += 64) {
    __syncthreads();
    {
      const float* vr0 = vb + (gbase + c0 + kp)*HID + dg*8;
      const float* vr1 = vr0 + HID;
      f4v u0 = *(const f4v*)vr0, u1 = *(const f4v*)(vr0 + 4);
      f4v w0 = *(const f4v*)vr1, w1 = *(const f4v*)(vr1 + 4);
#pragma unroll
      for (int i = 0; i < 4; ++i) {
        unsigned int p0 = (unsigned int)f2b(u0[i]) | ((unsigned int)f2b(w0[i]) << 16);
        unsigned int p1 = (unsigned int)f2b(u1[i]) | ((unsigned int)f2b(w1[i]) << 16);
        *(unsigned int*)&vt[dg*8 + i][kp] = p0;
        *(unsigned int*)&vt[dg*8 + 4 + i][kp] = p1;
      }
    }
    f4v s[4];
#pragma unroll
    for (int nt = 0; nt < 4; ++nt) {
      s8v bk = *(const s8v*)(kb + (gbase + c0 + nt*16 + col)*DKK + quad*8);
      s[nt] = __builtin_amdgcn_mfma_f32_16x16x32_bf16(aq, bk,
                (f4v){0.f,0.f,0.f,0.f}, 0, 0, 0);
    }
#pragma unroll
    for (int r = 0; r < 4; ++r) {
      float s0 = s[0][r]*rs, s1 = s[1][r]*rs, s2 = s[2][r]*rs, s3 = s[3][r]*rs;
      float mc = fmaxf(fmaxf(s0, s1), fmaxf(s2, s3));
#pragma unroll
      for (int off = 1; off < 16; off <<= 1) mc = fmaxf(mc, __shfl_xor(mc, off));
      float mn = fmaxf(mrow[r], mc);
      float al = expf(mrow[r] - mn);
      mrow[r] = mn;
      float p0 = expf(s0 - mn), p1 = expf(s1 - mn), p2 = expf(s2 - mn), p3 = expf(s3 - mn);
      float su = p0 + p1 + p2 + p3;
#pragma unroll
      for (int off = 1; off < 16; off <<= 1) su += __shfl_xor(su, off);
      lrow[r] = lrow[r]*al + su;
#pragma unroll
      for (int t = 0; t < 4; ++t) acc[t][r] *= al;
      int row = wv*16 + quad*4 + r;
      pl[row][col]      = f2b(p0);
      pl[row][16 + col] = f2b(p1);
      pl[row][32 + col] = f2b(p2);
      pl[row][48 + col] = f2b(p3);
    }
    __syncthreads();
#pragma unroll
    for (int ks = 0; ks < 2; ++ks) {
      s8v ap = *(const s8v*)&pl[wv*16 + col][ks*32 + quad*8];
#pragma unroll
      for (int nt = 0; nt < 4; ++nt) {
        s8v bv = *(const s8v*)&vt[nt*16 + col][ks*32 + quad*8];
        acc[nt] = __builtin_amdgcn_mfma_f32_16x16x32_bf16(ap, bv, acc[nt], 0, 0, 0);
      }
    }
  }

  float il[4];
#pragma unroll
  for (int r = 0; r < 4; ++r) il[r] = 1.f / lrow[r];
#pragma unroll
  for (int t = 0; t < 4; ++t) {
    int row = wv*16 + quad*4;
#pragma unroll
    for (int r = 0; r < 4; ++r)
      ob[row + r][t*16 + col] = acc[t][r] * il[r];
  }
  __syncthreads();
  int b = bg >> 2, g = bg & 3;
  float gg = f ? ((const float*)g1)[og1 + lane] : b2f(((const bf16*)g1)[og1 + lane]);
  float bb = f ? ((const float*)b1)[ob1 + lane] : b2f(((const bf16*)b1)[ob1 + lane]);
#pragma unroll
  for (int rr = 0; rr < 16; ++rr) {
    int rl = wv*16 + rr;
    int n = n0 + rl;
    float val = ob[rl][lane];
    float s = val;
#pragma unroll
    for (int off = 32; off; off >>= 1) s += __shfl_xor(s, off);
    float m = s*(1.f/HID);
    float d = val - m, sq = d*d;
#pragma unroll
    for (int off = 32; off; off >>= 1) sq += __shfl_xor(sq, off);
    float r = rsqrtf(sq*(1.f/HID) + 1e-5f);
    float* zp = z + ((long)(b*NN + n)*SEGN + g)*HID;
    zp[lane] = d*r*gg + bb + zp[lane];   // LN(att) + x
  }
}

// ---------------------------------------------------------------- pool over segments
__global__ __launch_bounds__(64) void k_pool(const float* __restrict__ z,
    float* __restrict__ enc, int s) {
  int b = blockIdx.x >> 10, n = blockIdx.x & 1023, h = threadIdx.x;
  const float* zp = z + (long)(b*NN + n)*SEGN*HID;
  float a = 0;
#pragma unroll
  for (int g = 0; g < SEGN; ++g) a += zp[g*HID + h];
  enc[(long)(b*NN + n)*(2*HID) + s*HID + h] = a*0.25f;
}

// ---------------------------------------------------------------- final qkv proj (in_dim=128)
template <int F>
__device__ __forceinline__ void fqkv_body(const float* __restrict__ enc,
    const void* __restrict__ wq, const void* __restrict__ wk,
    const void* __restrict__ wv,
    unsigned short* __restrict__ q, unsigned short* __restrict__ k,
    float* __restrict__ v, float* xs) {
  long r = blockIdx.x;
  int t = threadIdx.x;
  xs[t] = enc[r*128 + t];
  __syncthreads();
  if (t < 32) {
    long wr = (long)t*128; float a = 0;
    for (int e = 0; e < 128; ++e) a += xs[e]*ldw<F>(wq, wr + e);
    q[r*DKK + t] = f2b(a);
  } else if (t < 64) {
    long wr = (long)(t-32)*128; float a = 0;
    for (int e = 0; e < 128; ++e) a += xs[e]*ldw<F>(wk, wr + e);
    k[r*DKK + (t-32)] = f2b(a);
  } else {
    long wr = (long)(t-64)*128; float a = 0;
    for (int e = 0; e < 128; ++e) a += xs[e]*ldw<F>(wv, wr + e);
    v[r*HID + (t-64)] = a;
  }
}
__global__ __launch_bounds__(128) void k_fqkv(const float* __restrict__ enc,
    const void* wq, const void* wk, const void* wv,
    unsigned short* q, unsigned short* k, float* v, const int* __restrict__ flag) {
  __shared__ float xs[2*HID];
  if (*flag) fqkv_body<1>(enc, wq, wk, wv, q, k, v, xs);
  else       fqkv_body<0>(enc, wq, wk, wv, q, k, v, xs);
}

// ---------------------------------------------------------------- final attention (flash-MFMA) -> d_out
__global__ __launch_bounds__(256) void k_fattn(
    const unsigned short* __restrict__ qb, const unsigned short* __restrict__ kb,
    const float* __restrict__ vb, void* __restrict__ outp,
    const int* __restrict__ flag) {
  __shared__ unsigned short vt[64][72];
  __shared__ unsigned short pl[64][72];
  __shared__ float ob[64][66];
  int tid = threadIdx.x;
  int wv = tid >> 6, lane = tid & 63;
  int col = lane & 15, quad = lane >> 4;
  int b = blockIdx.x >> 4;
  int n0 = (blockIdx.x & 15) * 64;
  long gbase = (long)b * NN;

  s8v aq = *(const s8v*)(qb + (gbase + n0 + wv*16 + col)*DKK + quad*8);

  f4v acc[4];
#pragma unroll
  for (int t = 0; t < 4; ++t) acc[t] = (f4v){0.f,0.f,0.f,0.f};
  float mrow[4] = {-1e30f,-1e30f,-1e30f,-1e30f};
  float lrow[4] = {0.f,0.f,0.f,0.f};
  const float rs = 0.17677669529663687f;

  int kp = (tid & 31) * 2, dg = tid >> 5;

  for (int c0 = 0; c0 < NN; c0 += 64) {
    __syncthreads();
    {
      const float* vr0 = vb + (gbase + c0 + kp)*HID + dg*8;
      const float* vr1 = vr0 + HID;
      f4v u0 = *(const f4v*)vr0, u1 = *(const f4v*)(vr0 + 4);
      f4v w0 = *(const f4v*)vr1, w1 = *(const f4v*)(vr1 + 4);
#pragma unroll
      for (int i = 0; i < 4; ++i) {
        unsigned int p0 = (unsigned int)f2b(u0[i]) | ((unsigned int)f2b(w0[i]) << 16);
        unsigned int p1 = (unsigned int)f2b(u1[i]) | ((unsigned int)f2b(w1[i]) << 16);
        *(unsigned int*)&vt[dg*8 + i][kp] = p0;
        *(unsigned int*)&vt[dg*8 + 4 + i][kp] = p1;
      }
    }
    f4v s[4];
#pragma unroll
    for (int nt = 0; nt < 4; ++nt) {
      s8v bk = *(const s8v*)(kb + (gbase + c0 + nt*16 + col)*DKK + quad*8);
      s[nt] = __builtin_amdgcn_mfma_f32_16x16x32_bf16(aq, bk,
                (f4v){0.f,0.f,0.f,0.f}, 0, 0, 0);
    }
#pragma unroll
    for (int r = 0; r < 4; ++r) {
      float s0 = s[0][r]*rs, s1 = s[1][r]*rs, s2 = s[2][r]*rs, s3 = s[3][r]*rs;
      float mc = fmaxf(fmaxf(s0, s1), fmaxf(s2, s3));
#pragma unroll
      for (int off = 1; off < 16; off <<= 1) mc = fmaxf(mc, __shfl_xor(mc, off));
      float mn = fmaxf(mrow[r], mc);
      float al = expf(mrow[r] - mn);
      mrow[r] = mn;
      float p0 = expf(s0 - mn), p1 = expf(s1 - mn), p2 = expf(s2 - mn), p3 = expf(s3 - mn);
      float su = p0 + p1 + p2 + p3;
#pragma unroll
      for (int off = 1; off < 16; off <<= 1) su += __shfl_xor(su, off);
      lrow[r] = lrow[r]*al + su;
#pragma unroll
      for (int t = 0; t < 4; ++t) acc[t][r] *= al;
      int row = wv*16 + quad*4 + r;
      pl[row][col]      = f2b(p0);
      pl[row][16 + col] = f2b(p1);
      pl[row][32 + col] = f2b(p2);
      pl[row][48 + col] = f2b(p3);
    }
    __syncthreads();
#pragma unroll
    for (int ks = 0; ks < 2; ++ks) {
      s8v ap = *(const s8v*)&pl[wv*16 + col][ks*32 + quad*8];
#pragma unroll
      for (int nt = 0; nt < 4; ++nt) {
        s8v bv = *(const s8v*)&vt[nt*16 + col][ks*32 + quad*8];
        acc[nt] = __builtin_amdgcn_mfma_f32_16x16x32_bf16(ap, bv, acc[nt], 0, 0, 0);
      }
    }
  }

  float il[4];
#pragma unroll
  for (int r = 0; r < 4; ++r) il[r] = 1.f / lrow[r];
#pragma unroll
  for (int t = 0; t < 4; ++t) {
    int row = wv*16 + quad*4;
#pragma unroll
    for (int r = 0; r < 4; ++r)
      ob[row + r][t*16 + col] = acc[t][r] * il[r];
  }
  __syncthreads();
  int f = *flag;
#pragma unroll
  for (int rr = 0; rr < 16; ++rr) {
    int rl = wv*16 + rr;
    long idx = (gbase + n0 + rl)*HID + lane;
    float val = ob[rl][lane];
    if (f) ((float*)outp)[idx] = val;
    else   ((bf16*)outp)[idx] = __float2bfloat16(val);
  }
}

// ================================================================ launch
extern "C" void kernel_launch(void* const* d_in, const int* in_sizes, int n_in,
                              void* d_out, int out_size, void* d_ws, size_t ws_size,
                              hipStream_t stream) {
  static const int EXP[30] = {
    49152, 49152, 384, 128, 49152, 768, 16384, 256,
    524288, 8192, 524288, 256, 256, 256, 256, 256,
    8192, 8192, 16384, 524288, 8192, 524288, 256, 256,
    256, 256, 256, 4096, 4096, 8192
  };
  const size_t NEED = (size_t)(1048576 + 524288 + 524288 + 524288 + 1048576) * 4 + 64;
  bool ok = (n_in == 30) && (ws_size >= NEED) && (out_size == BB*NN*HID);
  if (ok) for (int i = 0; i < 30; ++i) ok = ok && (in_sizes[i] == EXP[i]);
  if (!ok) {
    k_zero<<<(BB*NN*HID + 255)/256, 256, 0, stream>>>((unsigned short*)d_out, BB*NN*HID);
    return;
  }

  float* z   = (float*)d_ws;             // [4,1024,4,64]
  float* enc = z   + 1048576;            // [4,1024,128]
  float* qb  = enc + 524288;             // bf16 q [*,1024,32]
  float* kb  = qb  + 524288;             // bf16 k
  float* vb  = kb  + 524288;             // fp32 v [*,1024,64]
  int*  flag = (int*)(vb + 1048576);

  k_detect<<<1, 256, 0, stream>>>(d_in[0], flag);

  const void *i_traffic=d_in[0], *i_user=d_in[1], *i_pw=d_in[2], *i_pb=d_in[3],
    *i_mw=d_in[4], *i_mb=d_in[5], *i_ow=d_in[6], *i_ob=d_in[7], *i_f1w=d_in[8],
    *i_f1b=d_in[9], *i_f2w=d_in[10], *i_f2b=d_in[11], *i_l1g=d_in[12],
    *i_l1b=d_in[13], *i_l2g=d_in[14], *i_l2b=d_in[15], *i_gwq=d_in[16],
    *i_gwk=d_in[17], *i_gwv=d_in[18], *i_gf1w=d_in[19], *i_gf1b=d_in[20],
    *i_gf2w=d_in[21], *i_gf2b=d_in[22], *i_gl1g=d_in[23], *i_gl1b=d_in[24],
    *i_gl2g=d_in[25], *i_gl2b=d_in[26], *i_cwq=d_in[27], *i_cwk=d_in[28],
    *i_cwv=d_in[29];

  const int FFG = BB*NN*SEGN/FRW;        // 256 blocks
  const int TAG = BB*NN*SEGN/TT;         // 256 blocks

  for (int s = 0; s < 2; ++s) {
    const void* x = s ? i_user : i_traffic;
    k_patch<<<BB*NN, 256, 0, stream>>>(x, i_pw, (long)s*HID*SEGL, i_pb, (long)s*HID, z, flag);
    for (int i = 0; i < 2; ++i) {
      long si = s*2 + i;
      k_tattn<<<TAG, 256, 0, stream>>>(z,
          i_mw, si*3*HID*HID, i_mb, si*3*HID, i_ow, si*HID*HID, i_ob, si*HID,
          i_l1g, si*HID, i_l1b, si*HID, flag);
      k_ffmfma<<<FFG, 256, 0, stream>>>(z,
          i_f1w, si*FFD*HID, i_f1b, si*FFD, i_f2w, si*HID*FFD, i_f2b, si*HID,
          i_l2g, si*HID, i_l2b, si*HID, flag);
      k_gqkv<<<256, 256, 0, stream>>>(z,
          i_gwq, si*DKK*HID, i_gwk, si*DKK*HID, i_gwv, si*HID*HID,
          (unsigned short*)qb, (unsigned short*)kb, vb, flag);
      k_gattn<<<16*16, 256, 0, stream>>>(z,
          (const unsigned short*)qb, (const unsigned short*)kb, vb,
          i_gl1g, si*HID, i_gl1b, si*HID, flag);
      k_ffmfma<<<FFG, 256, 0, stream>>>(z,
          i_gf1w, si*FFD*HID, i_gf1b, si*FFD, i_gf2w, si*HID*FFD, i_gf2b, si*HID,
          i_gl2g, si*HID, i_gl2b, si*HID, flag);
    }
    k_pool<<<BB*NN, 64, 0, stream>>>(z, enc, s);
  }
  k_fqkv<<<BB*NN, 128, 0, stream>>>(enc, i_cwq, i_cwk, i_cwv,
      (unsigned short*)qb, (unsigned short*)kb, vb, flag);
  k_fattn<<<BB*16, 256, 0, stream>>>((const unsigned short*)qb,
      (const unsigned short*)kb, vb, d_out, flag);
}